// Round 1
// baseline (727.374 us; speedup 1.0000x reference)
//
#include <hip/hip_runtime.h>
#include <cstddef>
#include <cstdint>

// Problem constants (fixed by setup_inputs)
constexpr int B_SEG   = 4;
constexpr int N_C     = 4096;    // coarse points per batch
constexpr int M_F     = 16384;   // fine points per batch
constexpr int CIN     = 384;
constexpr int COUT    = 192;
constexpr int MT      = B_SEG * N_C;   // 16384 coarse rows
constexpr int MF      = B_SEG * M_F;   // 65536 fine rows
constexpr float LN_EPS = 1e-5f;

constexpr int NSEG    = 4;             // src-scan segments for KNN
constexpr int SEGLEN  = N_C / NSEG;    // 1024 src points per segment
constexpr int NDST    = 2;             // dst points per thread in K2a

typedef __bf16 bf16x8 __attribute__((ext_vector_type(8)));
typedef __bf16 bf16x4 __attribute__((ext_vector_type(4)));
typedef float  f32x4  __attribute__((ext_vector_type(4)));

// ---------------------------------------------------------------------------
// K0: one-time prep — transpose+convert weights to bf16 [n][k] layout so the
// GEMM kernels load B-fragments as contiguous 16B global reads.
// ---------------------------------------------------------------------------
__global__ __launch_bounds__(256) void k0_prep(
    const float* __restrict__ w2, const float* __restrict__ w1,
    __bf16* __restrict__ wt2, __bf16* __restrict__ wt1)
{
  int e = blockIdx.x * 256 + threadIdx.x;
  if (e < CIN * COUT) {                       // w2: [384][192] -> wt2 [192][384]
    int k = e / COUT, n = e % COUT;
    wt2[(size_t)n * CIN + k] = (__bf16)w2[e];
  }
  e -= CIN * COUT;
  if (e >= 0 && e < COUT * COUT) {            // w1: [192][192] -> wt1 [192][192]
    int k = e / COUT, n = e % COUT;
    wt1[(size_t)n * COUT + k] = (__bf16)w1[e];
  }
}

// ---------------------------------------------------------------------------
// K1: h = LN(feats) @ w2 + b2      [16384 x 384] x [384 x 192]
// Block: 256 thr = 4 waves, 64 rows. LN in registers -> bf16 A-tile in LDS
// (MFMA A-layout, rows padded +8 bf16 => 2-way bank alias, free).
// B-frags: direct global bf16x8 loads from pre-transposed wt2 (L1-hot).
// One __syncthreads total; K-loop has no barriers.
// ---------------------------------------------------------------------------
__global__ __launch_bounds__(256) void k1_ln_gemm(
    const float* __restrict__ feats, const float* __restrict__ ln_g,
    const float* __restrict__ ln_b, const __bf16* __restrict__ wt2,
    const float* __restrict__ b2, float* __restrict__ h)
{
  __shared__ __align__(16) __bf16 As[64][CIN + 8];
  const int tid = threadIdx.x;
  const int blk = blockIdx.x;

  // ---- Phase 1: LN (4 threads/row, 24 float4 each) ----
  {
    const int r = tid >> 2, q = tid & 3;
    const float* frow = feats + (size_t)(blk * 64 + r) * CIN;
    float4 v[24];
    float sum = 0.f, sumsq = 0.f;
#pragma unroll
    for (int i = 0; i < 24; ++i) {
      float4 t = *(const float4*)(frow + (q + 4 * i) * 4);
      v[i] = t;
      sum   += (t.x + t.y) + (t.z + t.w);
      sumsq += (t.x * t.x + t.y * t.y) + (t.z * t.z + t.w * t.w);
    }
    sum   += __shfl_xor(sum, 1);  sumsq += __shfl_xor(sumsq, 1);
    sum   += __shfl_xor(sum, 2);  sumsq += __shfl_xor(sumsq, 2);
    float mean = sum * (1.f / CIN);
    float var  = sumsq * (1.f / CIN) - mean * mean;
    if (var < 0.f) var = 0.f;
    float rs = rsqrtf(var + LN_EPS);
#pragma unroll
    for (int i = 0; i < 24; ++i) {
      float4 g4 = *(const float4*)(ln_g + (q + 4 * i) * 4);
      float4 b4 = *(const float4*)(ln_b + (q + 4 * i) * 4);
      bf16x4 o;
      o[0] = (__bf16)((v[i].x - mean) * rs * g4.x + b4.x);
      o[1] = (__bf16)((v[i].y - mean) * rs * g4.y + b4.y);
      o[2] = (__bf16)((v[i].z - mean) * rs * g4.z + b4.z);
      o[3] = (__bf16)((v[i].w - mean) * rs * g4.w + b4.w);
      *(bf16x4*)&As[r][(q + 4 * i) * 4] = o;
    }
  }
  __syncthreads();

  // ---- Phase 2: MFMA ----
  const int w = tid >> 6, lane = tid & 63, m = lane & 15, half = lane >> 4;
  f32x4 acc[12];
#pragma unroll
  for (int t = 0; t < 12; ++t) acc[t] = (f32x4){0.f, 0.f, 0.f, 0.f};

  const __bf16* Arow = &As[16 * w + m][half * 8];
  const __bf16* Bbase = wt2 + (size_t)m * CIN + half * 8;
#pragma unroll
  for (int ch = 0; ch < 12; ++ch) {
    bf16x8 a = *(const bf16x8*)(Arow + ch * 32);
#pragma unroll
    for (int t = 0; t < 12; ++t) {
      bf16x8 b = *(const bf16x8*)(Bbase + (size_t)(16 * t) * CIN + ch * 32);
      acc[t] = __builtin_amdgcn_mfma_f32_16x16x32_bf16(a, b, acc[t], 0, 0, 0);
    }
  }

  // ---- Epilogue: D layout col=lane&15, row=(lane>>4)*4+reg ----
  const int r0 = blk * 64 + 16 * w + half * 4;
#pragma unroll
  for (int t = 0; t < 12; ++t) {
    float bv = b2[16 * t + m];
#pragma unroll
    for (int reg = 0; reg < 4; ++reg)
      h[(size_t)(r0 + reg) * COUT + 16 * t + m] = acc[t][reg] + bv;
  }
}

// ---------------------------------------------------------------------------
// K2a helpers: exact-rounding distance (must stay bit-identical to the
// reference selection) and branchy ascending-j top-3 insert (strict < keeps
// earliest index on ties, matching jax.lax.top_k).
// ---------------------------------------------------------------------------
__device__ __forceinline__ float dist2_rn(float px, float py, float pz,
                                          float sx, float sy, float sz)
{
  float dx = __fsub_rn(px, sx);
  float dy = __fsub_rn(py, sy);
  float dz = __fsub_rn(pz, sz);
  return __fadd_rn(__fadd_rn(__fmul_rn(dx, dx), __fmul_rn(dy, dy)),
                   __fmul_rn(dz, dz));
}

__device__ __forceinline__ void ins3(float d2, int j,
    float& t0, float& t1, float& t2, int& j0, int& j1, int& j2)
{
  if (d2 < t2) {
    if (d2 < t1) {
      t2 = t1; j2 = j1;
      if (d2 < t0) { t1 = t0; j1 = j0; t0 = d2; j0 = j; }
      else         { t1 = d2; j1 = j; }
    } else { t2 = d2; j2 = j; }
  }
}

// ---------------------------------------------------------------------------
// K2a: partial 3-NN over one src segment per block.
// DS-pipe diet vs previous version:
//  - src points read as 3x ds_read_b128 per 4 points (was 12x ds_read_b32)
//  - 2 dst points per thread -> half the waves -> half the total DS instrs
// VALU work per pair unchanged (exact-rounding distance preserved).
// ---------------------------------------------------------------------------
__global__ __launch_bounds__(256) void k2a_knn_part(
    const float* __restrict__ xyz, const float* __restrict__ sxyz,
    float* __restrict__ pd2, int* __restrict__ pj)
{
  __shared__ __align__(16) float lds[SEGLEN * 3];
  const int tid  = threadIdx.x;
  const int dgrp = blockIdx.x >> 2;          // 512-dst group (0..127)
  const int seg  = blockIdx.x & 3;
  const int b    = dgrp >> 5;                // 32 groups per batch segment
  const float* src = xyz + ((size_t)b * N_C + (size_t)seg * SEGLEN) * 3;
  {
    const float4* s4 = (const float4*)src;
    float4* d4 = (float4*)lds;
#pragma unroll
    for (int i = 0; i < 3; ++i) d4[tid + 256 * i] = s4[tid + 256 * i];
  }
  const int dst0 = dgrp * (256 * NDST) + tid;
  const int dst1 = dst0 + 256;
  float px0 = sxyz[(size_t)dst0 * 3 + 0];
  float py0 = sxyz[(size_t)dst0 * 3 + 1];
  float pz0 = sxyz[(size_t)dst0 * 3 + 2];
  float px1 = sxyz[(size_t)dst1 * 3 + 0];
  float py1 = sxyz[(size_t)dst1 * 3 + 1];
  float pz1 = sxyz[(size_t)dst1 * 3 + 2];
  __syncthreads();

  float a0 = 1e30f, a1 = 1e30f, a2 = 1e30f;
  int   ia0 = -1, ia1 = -1, ia2 = -1;
  float b0 = 1e30f, b1v = 1e30f, b2v = 1e30f;
  int   ib0 = -1, ib1 = -1, ib2 = -1;

#pragma unroll 4
  for (int j4 = 0; j4 < SEGLEN; j4 += 4) {
    const f32x4 c0 = *(const f32x4*)&lds[3 * j4 + 0];  // x0 y0 z0 x1
    const f32x4 c1 = *(const f32x4*)&lds[3 * j4 + 4];  // y1 z1 x2 y2
    const f32x4 c2 = *(const f32x4*)&lds[3 * j4 + 8];  // z2 x3 y3 z3
    const float sx[4] = {c0[0], c0[3], c1[2], c2[1]};
    const float sy[4] = {c0[1], c1[0], c1[3], c2[2]};
    const float sz[4] = {c0[2], c1[1], c2[0], c2[3]};
#pragma unroll
    for (int u = 0; u < 4; ++u) {
      float dA = dist2_rn(px0, py0, pz0, sx[u], sy[u], sz[u]);
      float dB = dist2_rn(px1, py1, pz1, sx[u], sy[u], sz[u]);
      ins3(dA, j4 + u, a0, a1, a2, ia0, ia1, ia2);
      ins3(dB, j4 + u, b0, b1v, b2v, ib0, ib1, ib2);
    }
  }

  const int jb = b * N_C + seg * SEGLEN;
  {
    const size_t o = (size_t)dst0 * 16 + seg * 4;
    *(float4*)(pd2 + o) = make_float4(a0, a1, a2, 1e30f);
    *(int4*)(pj + o)    = make_int4(jb + ia0, jb + ia1, jb + ia2, 0x7fffffff);
  }
  {
    const size_t o = (size_t)dst1 * 16 + seg * 4;
    *(float4*)(pd2 + o) = make_float4(b0, b1v, b2v, 1e30f);
    *(int4*)(pj + o)    = make_int4(jb + ib0, jb + ib1, jb + ib2, 0x7fffffff);
  }
}

// ---------------------------------------------------------------------------
// K2b: merge partial lists -> final top-3 + weights (unchanged).
// ---------------------------------------------------------------------------
__global__ __launch_bounds__(256) void k2b_knn_merge(
    const float* __restrict__ pd2, const int* __restrict__ pj,
    int* __restrict__ knn_i, float* __restrict__ knn_w)
{
  const int dst = blockIdx.x * 256 + threadIdx.x;
  const size_t base = (size_t)dst * 16;
  float t0 = 1e30f, t1 = 1e30f, t2 = 1e30f;
  int   j0 = 0x7fffffff, j1 = 0x7fffffff, j2 = 0x7fffffff;
#pragma unroll
  for (int s = 0; s < 4; ++s) {
    float4 d4 = *(const float4*)(pd2 + base + s * 4);
    int4   i4 = *(const int4*)(pj + base + s * 4);
    float dc[4] = {d4.x, d4.y, d4.z, d4.w};
    int   ic[4] = {i4.x, i4.y, i4.z, i4.w};
#pragma unroll
    for (int k = 0; k < 4; ++k) {
      float d = dc[k]; int j = ic[k];
      bool lt2 = (d < t2) || (d == t2 && j < j2);
      if (lt2) {
        bool lt1 = (d < t1) || (d == t1 && j < j1);
        if (lt1) {
          t2 = t1; j2 = j1;
          bool lt0 = (d < t0) || (d == t0 && j < j0);
          if (lt0) { t1 = t0; j1 = j0; t0 = d; j0 = j; }
          else     { t1 = d; j1 = j; }
        } else { t2 = d; j2 = j; }
      }
    }
  }
  float d0 = sqrtf(t0), d1 = sqrtf(t1), d2s = sqrtf(t2);
  float r0 = 1.f / (d0 + 1e-8f);
  float r1 = 1.f / (d1 + 1e-8f);
  float r2 = 1.f / (d2s + 1e-8f);
  float inv = 1.f / (r0 + r1 + r2);
  knn_i[(size_t)dst * 3 + 0] = j0;
  knn_i[(size_t)dst * 3 + 1] = j1;
  knn_i[(size_t)dst * 3 + 2] = j2;
  knn_w[(size_t)dst * 3 + 0] = r0 * inv;
  knn_w[(size_t)dst * 3 + 1] = r1 * inv;
  knn_w[(size_t)dst * 3 + 2] = r2 * inv;
}

// ---------------------------------------------------------------------------
// K3: out = LN(support_feats) @ w1 + b1 + interp(h)   [65536 x 192] x [192 x 192]
// MFMA structure as K1 (K=192 -> 6 chunks). Epilogue now stages acc+bias into
// an LDS tile (union-overlaid with the bf16 A-tile; 49 KB -> 3 blocks/CU),
// then a float4-vectorized pass does the 3-NN gather + store:
// per thread 36x b128 loads + 12x b128 stores (was 144 + 48 scalar).
// ---------------------------------------------------------------------------
__global__ __launch_bounds__(256) void k3_ln_gemm_interp(
    const float* __restrict__ sfeats, const float* __restrict__ ln_g,
    const float* __restrict__ ln_b, const __bf16* __restrict__ wt1,
    const float* __restrict__ b1, const float* __restrict__ h,
    const int* __restrict__ knn_i, const float* __restrict__ knn_w,
    float* __restrict__ out)
{
  union SMem {
    __bf16 a[64][COUT + 8];    // 25.6 KB — LN'd A-tile (phases 1-2)
    float  c[64][COUT + 4];    // 50.2 KB — staged GEMM result (epilogue)
  };
  __shared__ __align__(16) SMem sm;
  const int tid = threadIdx.x;
  const int blk = blockIdx.x;

  // ---- Phase 1: LN (4 threads/row, 12 float4 each) ----
  {
    const int r = tid >> 2, q = tid & 3;
    const float* frow = sfeats + (size_t)(blk * 64 + r) * COUT;
    float4 v[12];
    float sum = 0.f, sumsq = 0.f;
#pragma unroll
    for (int i = 0; i < 12; ++i) {
      float4 t = *(const float4*)(frow + (q + 4 * i) * 4);
      v[i] = t;
      sum   += (t.x + t.y) + (t.z + t.w);
      sumsq += (t.x * t.x + t.y * t.y) + (t.z * t.z + t.w * t.w);
    }
    sum   += __shfl_xor(sum, 1);  sumsq += __shfl_xor(sumsq, 1);
    sum   += __shfl_xor(sum, 2);  sumsq += __shfl_xor(sumsq, 2);
    float mean = sum * (1.f / COUT);
    float var  = sumsq * (1.f / COUT) - mean * mean;
    if (var < 0.f) var = 0.f;
    float rs = rsqrtf(var + LN_EPS);
#pragma unroll
    for (int i = 0; i < 12; ++i) {
      float4 g4 = *(const float4*)(ln_g + (q + 4 * i) * 4);
      float4 b4 = *(const float4*)(ln_b + (q + 4 * i) * 4);
      bf16x4 o;
      o[0] = (__bf16)((v[i].x - mean) * rs * g4.x + b4.x);
      o[1] = (__bf16)((v[i].y - mean) * rs * g4.y + b4.y);
      o[2] = (__bf16)((v[i].z - mean) * rs * g4.z + b4.z);
      o[3] = (__bf16)((v[i].w - mean) * rs * g4.w + b4.w);
      *(bf16x4*)&sm.a[r][(q + 4 * i) * 4] = o;
    }
  }
  __syncthreads();

  // ---- Phase 2: MFMA ----
  const int w = tid >> 6, lane = tid & 63, m = lane & 15, half = lane >> 4;
  f32x4 acc[12];
#pragma unroll
  for (int t = 0; t < 12; ++t) acc[t] = (f32x4){0.f, 0.f, 0.f, 0.f};

  const __bf16* Arow = &sm.a[16 * w + m][half * 8];
  const __bf16* Bbase = wt1 + (size_t)m * COUT + half * 8;
#pragma unroll
  for (int ch = 0; ch < 6; ++ch) {
    bf16x8 a = *(const bf16x8*)(Arow + ch * 32);
#pragma unroll
    for (int t = 0; t < 12; ++t) {
      bf16x8 b = *(const bf16x8*)(Bbase + (size_t)(16 * t) * COUT + ch * 32);
      acc[t] = __builtin_amdgcn_mfma_f32_16x16x32_bf16(a, b, acc[t], 0, 0, 0);
    }
  }

  // ---- Stage acc+bias into LDS (all waves must be done reading sm.a) ----
  float bv[12];
#pragma unroll
  for (int t = 0; t < 12; ++t) bv[t] = b1[16 * t + m];
  __syncthreads();
  {
    const int rr = 16 * w + half * 4;
#pragma unroll
    for (int t = 0; t < 12; ++t)
#pragma unroll
      for (int reg = 0; reg < 4; ++reg)
        sm.c[rr + reg][16 * t + m] = acc[t][reg] + bv[t];
  }
  __syncthreads();

  // ---- Vectorized interp + store: 4 threads per row, float4 everywhere ----
  {
    const int r = tid >> 2, q = tid & 3;
    const int R = blk * 64 + r;
    int   i0 = knn_i[(size_t)R * 3 + 0];
    int   i1 = knn_i[(size_t)R * 3 + 1];
    int   i2 = knn_i[(size_t)R * 3 + 2];
    float w0 = knn_w[(size_t)R * 3 + 0];
    float w1v = knn_w[(size_t)R * 3 + 1];
    float w2v = knn_w[(size_t)R * 3 + 2];
    const float* h0 = h + (size_t)i0 * COUT;
    const float* h1 = h + (size_t)i1 * COUT;
    const float* h2 = h + (size_t)i2 * COUT;
    float* orow = out + (size_t)R * COUT;
#pragma unroll
    for (int i = 0; i < 12; ++i) {
      const int col = 16 * i + 4 * q;
      f32x4 cv = *(const f32x4*)&sm.c[r][col];
      f32x4 g0 = *(const f32x4*)(h0 + col);
      f32x4 g1 = *(const f32x4*)(h1 + col);
      f32x4 g2 = *(const f32x4*)(h2 + col);
      f32x4 o  = cv + w0 * g0 + w1v * g1 + w2v * g2;
      *(f32x4*)(orow + col) = o;
    }
  }
}

// ---------------------------------------------------------------------------
// K4: passthrough outputs — support_xyz copy + support_offset as float
// ---------------------------------------------------------------------------
__global__ __launch_bounds__(256) void k4_tail(
    const float* __restrict__ sxyz, const int* __restrict__ soff,
    float* __restrict__ out_tail)
{
  const int t = blockIdx.x * 256 + threadIdx.x;
  if (t < MF * 3) out_tail[t] = sxyz[t];
  if (t < B_SEG) out_tail[MF * 3 + t] = (float)soff[t];
}

// ---------------------------------------------------------------------------
extern "C" void kernel_launch(void* const* d_in, const int* in_sizes, int n_in,
                              void* d_out, int out_size, void* d_ws, size_t ws_size,
                              hipStream_t stream)
{
  const float* feats  = (const float*)d_in[0];
  const float* xyz    = (const float*)d_in[1];
  const float* sxyz   = (const float*)d_in[2];
  const float* sfeats = (const float*)d_in[3];
  const int*   soff   = (const int*)d_in[5];
  const float* ln1_g  = (const float*)d_in[6];
  const float* ln1_b  = (const float*)d_in[7];
  const float* w1     = (const float*)d_in[8];
  const float* b1     = (const float*)d_in[9];
  const float* ln2_g  = (const float*)d_in[10];
  const float* ln2_b  = (const float*)d_in[11];
  const float* w2     = (const float*)d_in[12];
  const float* b2     = (const float*)d_in[13];
  float* out = (float*)d_out;

  // workspace layout
  float*  h     = (float*)d_ws;                      // 16384*192 f32 (12.6 MB)
  int*    knn_i = (int*)(h + (size_t)MT * COUT);     // 65536*3 ints
  float*  knn_w = (float*)(knn_i + (size_t)MF * 3);  // 65536*3 floats
  float*  pd2   = knn_w + (size_t)MF * 3;            // 65536*16 floats (4 MB)
  int*    pj    = (int*)(pd2 + (size_t)MF * 16);     // 65536*16 ints   (4 MB)
  __bf16* wt2   = (__bf16*)(pj + (size_t)MF * 16);   // 192*384 bf16
  __bf16* wt1   = wt2 + (size_t)COUT * CIN;          // 192*192 bf16

  k0_prep<<<(CIN * COUT + COUT * COUT) / 256, 256, 0, stream>>>(w2, w1, wt2, wt1);
  k1_ln_gemm<<<MT / 64, 256, 0, stream>>>(feats, ln2_g, ln2_b, wt2, b2, h);
  k2a_knn_part<<<(MF / (256 * NDST)) * NSEG, 256, 0, stream>>>(xyz, sxyz, pd2, pj);
  k2b_knn_merge<<<MF / 256, 256, 0, stream>>>(pd2, pj, knn_i, knn_w);
  k3_ln_gemm_interp<<<MF / 64, 256, 0, stream>>>(sfeats, ln1_g, ln1_b, wt1, b1,
                                                 h, knn_i, knn_w, out);
  k4_tail<<<(MF * 3) / 256, 256, 0, stream>>>(sxyz, soff, out + (size_t)MF * COUT);
}

// Round 2
// 724.357 us; speedup vs baseline: 1.0042x; 1.0042x over previous
//
#include <hip/hip_runtime.h>
#include <cstddef>
#include <cstdint>

// Problem constants (fixed by setup_inputs)
constexpr int B_SEG   = 4;
constexpr int N_C     = 4096;    // coarse points per batch
constexpr int M_F     = 16384;   // fine points per batch
constexpr int CIN     = 384;
constexpr int COUT    = 192;
constexpr int MT      = B_SEG * N_C;   // 16384 coarse rows
constexpr int MF      = B_SEG * M_F;   // 65536 fine rows
constexpr float LN_EPS = 1e-5f;

constexpr int NSEG    = 4;             // src-scan segments for KNN
constexpr int SEGLEN  = N_C / NSEG;    // 1024 src points per segment
constexpr int NDST    = 2;             // dst points per thread in K2a

typedef __bf16 bf16x8 __attribute__((ext_vector_type(8)));
typedef __bf16 bf16x4 __attribute__((ext_vector_type(4)));
typedef float  f32x4  __attribute__((ext_vector_type(4)));

// ---------------------------------------------------------------------------
// K0: one-time prep — transpose+convert weights to bf16 [n][k] layout so the
// GEMM kernels load B-fragments as contiguous 16B global reads.
// ---------------------------------------------------------------------------
__global__ __launch_bounds__(256) void k0_prep(
    const float* __restrict__ w2, const float* __restrict__ w1,
    __bf16* __restrict__ wt2, __bf16* __restrict__ wt1)
{
  int e = blockIdx.x * 256 + threadIdx.x;
  if (e < CIN * COUT) {                       // w2: [384][192] -> wt2 [192][384]
    int k = e / COUT, n = e % COUT;
    wt2[(size_t)n * CIN + k] = (__bf16)w2[e];
  }
  e -= CIN * COUT;
  if (e >= 0 && e < COUT * COUT) {            // w1: [192][192] -> wt1 [192][192]
    int k = e / COUT, n = e % COUT;
    wt1[(size_t)n * COUT + k] = (__bf16)w1[e];
  }
}

// ---------------------------------------------------------------------------
// K1: h = LN(feats) @ w2 + b2      [16384 x 384] x [384 x 192]
// Block: 256 thr = 4 waves, 64 rows. LN in registers -> bf16 A-tile in LDS
// (MFMA A-layout, rows padded +8 bf16 => 2-way bank alias, free).
// B-frags: direct global bf16x8 loads from pre-transposed wt2 (L1-hot).
// One __syncthreads total; K-loop has no barriers.
// ---------------------------------------------------------------------------
__global__ __launch_bounds__(256) void k1_ln_gemm(
    const float* __restrict__ feats, const float* __restrict__ ln_g,
    const float* __restrict__ ln_b, const __bf16* __restrict__ wt2,
    const float* __restrict__ b2, float* __restrict__ h)
{
  __shared__ __align__(16) __bf16 As[64][CIN + 8];
  const int tid = threadIdx.x;
  const int blk = blockIdx.x;

  // ---- Phase 1: LN (4 threads/row, 24 float4 each) ----
  {
    const int r = tid >> 2, q = tid & 3;
    const float* frow = feats + (size_t)(blk * 64 + r) * CIN;
    float4 v[24];
    float sum = 0.f, sumsq = 0.f;
#pragma unroll
    for (int i = 0; i < 24; ++i) {
      float4 t = *(const float4*)(frow + (q + 4 * i) * 4);
      v[i] = t;
      sum   += (t.x + t.y) + (t.z + t.w);
      sumsq += (t.x * t.x + t.y * t.y) + (t.z * t.z + t.w * t.w);
    }
    sum   += __shfl_xor(sum, 1);  sumsq += __shfl_xor(sumsq, 1);
    sum   += __shfl_xor(sum, 2);  sumsq += __shfl_xor(sumsq, 2);
    float mean = sum * (1.f / CIN);
    float var  = sumsq * (1.f / CIN) - mean * mean;
    if (var < 0.f) var = 0.f;
    float rs = rsqrtf(var + LN_EPS);
#pragma unroll
    for (int i = 0; i < 24; ++i) {
      float4 g4 = *(const float4*)(ln_g + (q + 4 * i) * 4);
      float4 b4 = *(const float4*)(ln_b + (q + 4 * i) * 4);
      bf16x4 o;
      o[0] = (__bf16)((v[i].x - mean) * rs * g4.x + b4.x);
      o[1] = (__bf16)((v[i].y - mean) * rs * g4.y + b4.y);
      o[2] = (__bf16)((v[i].z - mean) * rs * g4.z + b4.z);
      o[3] = (__bf16)((v[i].w - mean) * rs * g4.w + b4.w);
      *(bf16x4*)&As[r][(q + 4 * i) * 4] = o;
    }
  }
  __syncthreads();

  // ---- Phase 2: MFMA ----
  const int w = tid >> 6, lane = tid & 63, m = lane & 15, half = lane >> 4;
  f32x4 acc[12];
#pragma unroll
  for (int t = 0; t < 12; ++t) acc[t] = (f32x4){0.f, 0.f, 0.f, 0.f};

  const __bf16* Arow = &As[16 * w + m][half * 8];
  const __bf16* Bbase = wt2 + (size_t)m * CIN + half * 8;
#pragma unroll
  for (int ch = 0; ch < 12; ++ch) {
    bf16x8 a = *(const bf16x8*)(Arow + ch * 32);
#pragma unroll
    for (int t = 0; t < 12; ++t) {
      bf16x8 b = *(const bf16x8*)(Bbase + (size_t)(16 * t) * CIN + ch * 32);
      acc[t] = __builtin_amdgcn_mfma_f32_16x16x32_bf16(a, b, acc[t], 0, 0, 0);
    }
  }

  // ---- Epilogue: D layout col=lane&15, row=(lane>>4)*4+reg ----
  const int r0 = blk * 64 + 16 * w + half * 4;
#pragma unroll
  for (int t = 0; t < 12; ++t) {
    float bv = b2[16 * t + m];
#pragma unroll
    for (int reg = 0; reg < 4; ++reg)
      h[(size_t)(r0 + reg) * COUT + 16 * t + m] = acc[t][reg] + bv;
  }
}

// ---------------------------------------------------------------------------
// K2a helpers: exact-rounding distance (must stay bit-identical to the
// reference selection) and branchy ascending-j top-3 insert (strict < keeps
// earliest index on ties, matching jax.lax.top_k).
// ---------------------------------------------------------------------------
__device__ __forceinline__ float dist2_rn(float px, float py, float pz,
                                          float sx, float sy, float sz)
{
  float dx = __fsub_rn(px, sx);
  float dy = __fsub_rn(py, sy);
  float dz = __fsub_rn(pz, sz);
  return __fadd_rn(__fadd_rn(__fmul_rn(dx, dx), __fmul_rn(dy, dy)),
                   __fmul_rn(dz, dz));
}

__device__ __forceinline__ void ins3(float d2, int j,
    float& t0, float& t1, float& t2, int& j0, int& j1, int& j2)
{
  if (d2 < t2) {
    if (d2 < t1) {
      t2 = t1; j2 = j1;
      if (d2 < t0) { t1 = t0; j1 = j0; t0 = d2; j0 = j; }
      else         { t1 = d2; j1 = j; }
    } else { t2 = d2; j2 = j; }
  }
}

// ---------------------------------------------------------------------------
// K2a: partial 3-NN over one src segment per block.
// R2 regression post-mortem: AoS f32x4 unpack via float arrays -> scratch
// spills (WRITE_SIZE 23MB, VALUBusy 13%). This version:
//  - LDS in SoA (lx/ly/lz), inner loop reads 4 points as 3x ds_read_b128
//    (0.75 DS instr/point vs 3) — all unpacking via CONSTANT-index vector
//    components into named scalars; no arrays anywhere.
//  - NDST=2 halves wave-scans; DS cycles/CU ~31us, matching the VALU floor.
// ---------------------------------------------------------------------------
__global__ __launch_bounds__(256) void k2a_knn_part(
    const float* __restrict__ xyz, const float* __restrict__ sxyz,
    float* __restrict__ pd2, int* __restrict__ pj)
{
  __shared__ __align__(16) float lx[SEGLEN];
  __shared__ __align__(16) float ly[SEGLEN];
  __shared__ __align__(16) float lz[SEGLEN];
  const int tid  = threadIdx.x;
  const int dgrp = blockIdx.x >> 2;          // 512-dst group (0..127)
  const int seg  = blockIdx.x & 3;
  const int b    = dgrp >> 5;                // 32 groups per batch segment
  const float* src = xyz + ((size_t)b * N_C + (size_t)seg * SEGLEN) * 3;

  // ---- SoA staging: thread t transposes points 4t..4t+3 in registers ----
  {
    const float4* s4 = (const float4*)src + tid * 3;  // 48B per thread, coalesced
    float4 f0 = s4[0];   // x0 y0 z0 x1
    float4 f1 = s4[1];   // y1 z1 x2 y2
    float4 f2 = s4[2];   // z2 x3 y3 z3
    *(float4*)&lx[4 * tid] = make_float4(f0.x, f0.w, f1.z, f2.y);
    *(float4*)&ly[4 * tid] = make_float4(f0.y, f1.x, f1.w, f2.z);
    *(float4*)&lz[4 * tid] = make_float4(f0.z, f1.y, f2.x, f2.w);
  }
  const int dst0 = dgrp * (256 * NDST) + tid;
  const int dst1 = dst0 + 256;
  float px0 = sxyz[(size_t)dst0 * 3 + 0];
  float py0 = sxyz[(size_t)dst0 * 3 + 1];
  float pz0 = sxyz[(size_t)dst0 * 3 + 2];
  float px1 = sxyz[(size_t)dst1 * 3 + 0];
  float py1 = sxyz[(size_t)dst1 * 3 + 1];
  float pz1 = sxyz[(size_t)dst1 * 3 + 2];
  __syncthreads();

  float a0 = 1e30f, a1 = 1e30f, a2 = 1e30f;
  int   ia0 = -1, ia1 = -1, ia2 = -1;
  float c0 = 1e30f, c1 = 1e30f, c2 = 1e30f;
  int   ic0 = -1, ic1 = -1, ic2 = -1;

#pragma unroll 2
  for (int j = 0; j < SEGLEN; j += 4) {
    const f32x4 X = *(const f32x4*)&lx[j];
    const f32x4 Y = *(const f32x4*)&ly[j];
    const f32x4 Z = *(const f32x4*)&lz[j];
    float d;
    d = dist2_rn(px0, py0, pz0, X[0], Y[0], Z[0]); ins3(d, j + 0, a0, a1, a2, ia0, ia1, ia2);
    d = dist2_rn(px1, py1, pz1, X[0], Y[0], Z[0]); ins3(d, j + 0, c0, c1, c2, ic0, ic1, ic2);
    d = dist2_rn(px0, py0, pz0, X[1], Y[1], Z[1]); ins3(d, j + 1, a0, a1, a2, ia0, ia1, ia2);
    d = dist2_rn(px1, py1, pz1, X[1], Y[1], Z[1]); ins3(d, j + 1, c0, c1, c2, ic0, ic1, ic2);
    d = dist2_rn(px0, py0, pz0, X[2], Y[2], Z[2]); ins3(d, j + 2, a0, a1, a2, ia0, ia1, ia2);
    d = dist2_rn(px1, py1, pz1, X[2], Y[2], Z[2]); ins3(d, j + 2, c0, c1, c2, ic0, ic1, ic2);
    d = dist2_rn(px0, py0, pz0, X[3], Y[3], Z[3]); ins3(d, j + 3, a0, a1, a2, ia0, ia1, ia2);
    d = dist2_rn(px1, py1, pz1, X[3], Y[3], Z[3]); ins3(d, j + 3, c0, c1, c2, ic0, ic1, ic2);
  }

  const int jb = b * N_C + seg * SEGLEN;
  {
    const size_t o = (size_t)dst0 * 16 + seg * 4;
    *(float4*)(pd2 + o) = make_float4(a0, a1, a2, 1e30f);
    *(int4*)(pj + o)    = make_int4(jb + ia0, jb + ia1, jb + ia2, 0x7fffffff);
  }
  {
    const size_t o = (size_t)dst1 * 16 + seg * 4;
    *(float4*)(pd2 + o) = make_float4(c0, c1, c2, 1e30f);
    *(int4*)(pj + o)    = make_int4(jb + ic0, jb + ic1, jb + ic2, 0x7fffffff);
  }
}

// ---------------------------------------------------------------------------
// K2b: merge partial lists -> final top-3 + weights (unchanged).
// ---------------------------------------------------------------------------
__global__ __launch_bounds__(256) void k2b_knn_merge(
    const float* __restrict__ pd2, const int* __restrict__ pj,
    int* __restrict__ knn_i, float* __restrict__ knn_w)
{
  const int dst = blockIdx.x * 256 + threadIdx.x;
  const size_t base = (size_t)dst * 16;
  float t0 = 1e30f, t1 = 1e30f, t2 = 1e30f;
  int   j0 = 0x7fffffff, j1 = 0x7fffffff, j2 = 0x7fffffff;
#pragma unroll
  for (int s = 0; s < 4; ++s) {
    float4 d4 = *(const float4*)(pd2 + base + s * 4);
    int4   i4 = *(const int4*)(pj + base + s * 4);
    float dc[4] = {d4.x, d4.y, d4.z, d4.w};
    int   ic[4] = {i4.x, i4.y, i4.z, i4.w};
#pragma unroll
    for (int k = 0; k < 4; ++k) {
      float d = dc[k]; int j = ic[k];
      bool lt2 = (d < t2) || (d == t2 && j < j2);
      if (lt2) {
        bool lt1 = (d < t1) || (d == t1 && j < j1);
        if (lt1) {
          t2 = t1; j2 = j1;
          bool lt0 = (d < t0) || (d == t0 && j < j0);
          if (lt0) { t1 = t0; j1 = j0; t0 = d; j0 = j; }
          else     { t1 = d; j1 = j; }
        } else { t2 = d; j2 = j; }
      }
    }
  }
  float d0 = sqrtf(t0), d1 = sqrtf(t1), d2s = sqrtf(t2);
  float r0 = 1.f / (d0 + 1e-8f);
  float r1 = 1.f / (d1 + 1e-8f);
  float r2 = 1.f / (d2s + 1e-8f);
  float inv = 1.f / (r0 + r1 + r2);
  knn_i[(size_t)dst * 3 + 0] = j0;
  knn_i[(size_t)dst * 3 + 1] = j1;
  knn_i[(size_t)dst * 3 + 2] = j2;
  knn_w[(size_t)dst * 3 + 0] = r0 * inv;
  knn_w[(size_t)dst * 3 + 1] = r1 * inv;
  knn_w[(size_t)dst * 3 + 2] = r2 * inv;
}

// ---------------------------------------------------------------------------
// K3: out = LN(support_feats) @ w1 + b1 + interp(h)   [65536 x 192] x [192 x 192]
// MFMA structure as K1 (K=192 -> 6 chunks). Epilogue stages acc+bias into an
// LDS tile (union-overlaid with the bf16 A-tile; ~50 KB -> 3 blocks/CU), then
// a float4-vectorized pass does the 3-NN gather + store.
// ---------------------------------------------------------------------------
__global__ __launch_bounds__(256) void k3_ln_gemm_interp(
    const float* __restrict__ sfeats, const float* __restrict__ ln_g,
    const float* __restrict__ ln_b, const __bf16* __restrict__ wt1,
    const float* __restrict__ b1, const float* __restrict__ h,
    const int* __restrict__ knn_i, const float* __restrict__ knn_w,
    float* __restrict__ out)
{
  union SMem {
    __bf16 a[64][COUT + 8];    // 25.6 KB — LN'd A-tile (phases 1-2)
    float  c[64][COUT + 4];    // 50.2 KB — staged GEMM result (epilogue)
  };
  __shared__ __align__(16) SMem sm;
  const int tid = threadIdx.x;
  const int blk = blockIdx.x;

  // ---- Phase 1: LN (4 threads/row, 12 float4 each) ----
  {
    const int r = tid >> 2, q = tid & 3;
    const float* frow = sfeats + (size_t)(blk * 64 + r) * COUT;
    float4 v[12];
    float sum = 0.f, sumsq = 0.f;
#pragma unroll
    for (int i = 0; i < 12; ++i) {
      float4 t = *(const float4*)(frow + (q + 4 * i) * 4);
      v[i] = t;
      sum   += (t.x + t.y) + (t.z + t.w);
      sumsq += (t.x * t.x + t.y * t.y) + (t.z * t.z + t.w * t.w);
    }
    sum   += __shfl_xor(sum, 1);  sumsq += __shfl_xor(sumsq, 1);
    sum   += __shfl_xor(sum, 2);  sumsq += __shfl_xor(sumsq, 2);
    float mean = sum * (1.f / COUT);
    float var  = sumsq * (1.f / COUT) - mean * mean;
    if (var < 0.f) var = 0.f;
    float rs = rsqrtf(var + LN_EPS);
#pragma unroll
    for (int i = 0; i < 12; ++i) {
      float4 g4 = *(const float4*)(ln_g + (q + 4 * i) * 4);
      float4 b4 = *(const float4*)(ln_b + (q + 4 * i) * 4);
      bf16x4 o;
      o[0] = (__bf16)((v[i].x - mean) * rs * g4.x + b4.x);
      o[1] = (__bf16)((v[i].y - mean) * rs * g4.y + b4.y);
      o[2] = (__bf16)((v[i].z - mean) * rs * g4.z + b4.z);
      o[3] = (__bf16)((v[i].w - mean) * rs * g4.w + b4.w);
      *(bf16x4*)&sm.a[r][(q + 4 * i) * 4] = o;
    }
  }
  __syncthreads();

  // ---- Phase 2: MFMA ----
  const int w = tid >> 6, lane = tid & 63, m = lane & 15, half = lane >> 4;
  f32x4 acc[12];
#pragma unroll
  for (int t = 0; t < 12; ++t) acc[t] = (f32x4){0.f, 0.f, 0.f, 0.f};

  const __bf16* Arow = &sm.a[16 * w + m][half * 8];
  const __bf16* Bbase = wt1 + (size_t)m * COUT + half * 8;
#pragma unroll
  for (int ch = 0; ch < 6; ++ch) {
    bf16x8 a = *(const bf16x8*)(Arow + ch * 32);
#pragma unroll
    for (int t = 0; t < 12; ++t) {
      bf16x8 b = *(const bf16x8*)(Bbase + (size_t)(16 * t) * COUT + ch * 32);
      acc[t] = __builtin_amdgcn_mfma_f32_16x16x32_bf16(a, b, acc[t], 0, 0, 0);
    }
  }

  // ---- Stage acc+bias into LDS (all waves must be done reading sm.a) ----
  float bv[12];
#pragma unroll
  for (int t = 0; t < 12; ++t) bv[t] = b1[16 * t + m];
  __syncthreads();
  {
    const int rr = 16 * w + half * 4;
#pragma unroll
    for (int t = 0; t < 12; ++t)
#pragma unroll
      for (int reg = 0; reg < 4; ++reg)
        sm.c[rr + reg][16 * t + m] = acc[t][reg] + bv[t];
  }
  __syncthreads();

  // ---- Vectorized interp + store: 4 threads per row, float4 everywhere ----
  {
    const int r = tid >> 2, q = tid & 3;
    const int R = blk * 64 + r;
    int   i0 = knn_i[(size_t)R * 3 + 0];
    int   i1 = knn_i[(size_t)R * 3 + 1];
    int   i2 = knn_i[(size_t)R * 3 + 2];
    float w0 = knn_w[(size_t)R * 3 + 0];
    float w1v = knn_w[(size_t)R * 3 + 1];
    float w2v = knn_w[(size_t)R * 3 + 2];
    const float* h0 = h + (size_t)i0 * COUT;
    const float* h1 = h + (size_t)i1 * COUT;
    const float* h2 = h + (size_t)i2 * COUT;
    float* orow = out + (size_t)R * COUT;
#pragma unroll
    for (int i = 0; i < 12; ++i) {
      const int col = 16 * i + 4 * q;
      f32x4 cv = *(const f32x4*)&sm.c[r][col];
      f32x4 g0 = *(const f32x4*)(h0 + col);
      f32x4 g1 = *(const f32x4*)(h1 + col);
      f32x4 g2 = *(const f32x4*)(h2 + col);
      f32x4 o  = cv + w0 * g0 + w1v * g1 + w2v * g2;
      *(f32x4*)(orow + col) = o;
    }
  }
}

// ---------------------------------------------------------------------------
// K4: passthrough outputs — support_xyz copy + support_offset as float
// ---------------------------------------------------------------------------
__global__ __launch_bounds__(256) void k4_tail(
    const float* __restrict__ sxyz, const int* __restrict__ soff,
    float* __restrict__ out_tail)
{
  const int t = blockIdx.x * 256 + threadIdx.x;
  if (t < MF * 3) out_tail[t] = sxyz[t];
  if (t < B_SEG) out_tail[MF * 3 + t] = (float)soff[t];
}

// ---------------------------------------------------------------------------
extern "C" void kernel_launch(void* const* d_in, const int* in_sizes, int n_in,
                              void* d_out, int out_size, void* d_ws, size_t ws_size,
                              hipStream_t stream)
{
  const float* feats  = (const float*)d_in[0];
  const float* xyz    = (const float*)d_in[1];
  const float* sxyz   = (const float*)d_in[2];
  const float* sfeats = (const float*)d_in[3];
  const int*   soff   = (const int*)d_in[5];
  const float* ln1_g  = (const float*)d_in[6];
  const float* ln1_b  = (const float*)d_in[7];
  const float* w1     = (const float*)d_in[8];
  const float* b1     = (const float*)d_in[9];
  const float* ln2_g  = (const float*)d_in[10];
  const float* ln2_b  = (const float*)d_in[11];
  const float* w2     = (const float*)d_in[12];
  const float* b2     = (const float*)d_in[13];
  float* out = (float*)d_out;

  // workspace layout
  float*  h     = (float*)d_ws;                      // 16384*192 f32 (12.6 MB)
  int*    knn_i = (int*)(h + (size_t)MT * COUT);     // 65536*3 ints
  float*  knn_w = (float*)(knn_i + (size_t)MF * 3);  // 65536*3 floats
  float*  pd2   = knn_w + (size_t)MF * 3;            // 65536*16 floats (4 MB)
  int*    pj    = (int*)(pd2 + (size_t)MF * 16);     // 65536*16 ints   (4 MB)
  __bf16* wt2   = (__bf16*)(pj + (size_t)MF * 16);   // 192*384 bf16
  __bf16* wt1   = wt2 + (size_t)COUT * CIN;          // 192*192 bf16

  k0_prep<<<(CIN * COUT + COUT * COUT) / 256, 256, 0, stream>>>(w2, w1, wt2, wt1);
  k1_ln_gemm<<<MT / 64, 256, 0, stream>>>(feats, ln2_g, ln2_b, wt2, b2, h);
  k2a_knn_part<<<(MF / (256 * NDST)) * NSEG, 256, 0, stream>>>(xyz, sxyz, pd2, pj);
  k2b_knn_merge<<<MF / 256, 256, 0, stream>>>(pd2, pj, knn_i, knn_w);
  k3_ln_gemm_interp<<<MF / 64, 256, 0, stream>>>(sfeats, ln1_g, ln1_b, wt1, b1,
                                                 h, knn_i, knn_w, out);
  k4_tail<<<(MF * 3) / 256, 256, 0, stream>>>(sxyz, soff, out + (size_t)MF * COUT);
}

// Round 3
// 348.301 us; speedup vs baseline: 2.0883x; 2.0797x over previous
//
#include <hip/hip_runtime.h>
#include <cstddef>
#include <cstdint>

// Problem constants (fixed by setup_inputs)
constexpr int B_SEG   = 4;
constexpr int N_C     = 4096;    // coarse points per batch
constexpr int M_F     = 16384;   // fine points per batch
constexpr int CIN     = 384;
constexpr int COUT    = 192;
constexpr int MT      = B_SEG * N_C;   // 16384 coarse rows
constexpr int MF      = B_SEG * M_F;   // 65536 fine rows
constexpr float LN_EPS = 1e-5f;

constexpr int NSEG    = 4;             // src-scan segments for KNN
constexpr int SEGLEN  = N_C / NSEG;    // 1024 src points per segment

typedef __bf16 bf16x8 __attribute__((ext_vector_type(8)));
typedef __bf16 bf16x4 __attribute__((ext_vector_type(4)));
typedef float  f32x4  __attribute__((ext_vector_type(4)));

// ---------------------------------------------------------------------------
// K0: one-time prep — transpose+convert weights to bf16 [n][k] layout so the
// GEMM kernels load B-fragments as contiguous 16B global reads.
// ---------------------------------------------------------------------------
__global__ __launch_bounds__(256) void k0_prep(
    const float* __restrict__ w2, const float* __restrict__ w1,
    __bf16* __restrict__ wt2, __bf16* __restrict__ wt1)
{
  int e = blockIdx.x * 256 + threadIdx.x;
  if (e < CIN * COUT) {                       // w2: [384][192] -> wt2 [192][384]
    int k = e / COUT, n = e % COUT;
    wt2[(size_t)n * CIN + k] = (__bf16)w2[e];
  }
  e -= CIN * COUT;
  if (e >= 0 && e < COUT * COUT) {            // w1: [192][192] -> wt1 [192][192]
    int k = e / COUT, n = e % COUT;
    wt1[(size_t)n * COUT + k] = (__bf16)w1[e];
  }
}

// ---------------------------------------------------------------------------
// K1: h = LN(feats) @ w2 + b2      [16384 x 384] x [384 x 192]
// Block: 256 thr = 4 waves, 64 rows. LN in registers -> bf16 A-tile in LDS.
// B-frags: direct global bf16x8 loads from pre-transposed wt2 (L1-hot).
// ---------------------------------------------------------------------------
__global__ __launch_bounds__(256) void k1_ln_gemm(
    const float* __restrict__ feats, const float* __restrict__ ln_g,
    const float* __restrict__ ln_b, const __bf16* __restrict__ wt2,
    const float* __restrict__ b2, float* __restrict__ h)
{
  __shared__ __align__(16) __bf16 As[64][CIN + 8];
  const int tid = threadIdx.x;
  const int blk = blockIdx.x;

  // ---- Phase 1: LN (4 threads/row, 24 float4 each) ----
  {
    const int r = tid >> 2, q = tid & 3;
    const float* frow = feats + (size_t)(blk * 64 + r) * CIN;
    float4 v[24];
    float sum = 0.f, sumsq = 0.f;
#pragma unroll
    for (int i = 0; i < 24; ++i) {
      float4 t = *(const float4*)(frow + (q + 4 * i) * 4);
      v[i] = t;
      sum   += (t.x + t.y) + (t.z + t.w);
      sumsq += (t.x * t.x + t.y * t.y) + (t.z * t.z + t.w * t.w);
    }
    sum   += __shfl_xor(sum, 1);  sumsq += __shfl_xor(sumsq, 1);
    sum   += __shfl_xor(sum, 2);  sumsq += __shfl_xor(sumsq, 2);
    float mean = sum * (1.f / CIN);
    float var  = sumsq * (1.f / CIN) - mean * mean;
    if (var < 0.f) var = 0.f;
    float rs = rsqrtf(var + LN_EPS);
#pragma unroll
    for (int i = 0; i < 24; ++i) {
      float4 g4 = *(const float4*)(ln_g + (q + 4 * i) * 4);
      float4 b4 = *(const float4*)(ln_b + (q + 4 * i) * 4);
      bf16x4 o;
      o[0] = (__bf16)((v[i].x - mean) * rs * g4.x + b4.x);
      o[1] = (__bf16)((v[i].y - mean) * rs * g4.y + b4.y);
      o[2] = (__bf16)((v[i].z - mean) * rs * g4.z + b4.z);
      o[3] = (__bf16)((v[i].w - mean) * rs * g4.w + b4.w);
      *(bf16x4*)&As[r][(q + 4 * i) * 4] = o;
    }
  }
  __syncthreads();

  // ---- Phase 2: MFMA ----
  const int w = tid >> 6, lane = tid & 63, m = lane & 15, half = lane >> 4;
  f32x4 acc[12];
#pragma unroll
  for (int t = 0; t < 12; ++t) acc[t] = (f32x4){0.f, 0.f, 0.f, 0.f};

  const __bf16* Arow = &As[16 * w + m][half * 8];
  const __bf16* Bbase = wt2 + (size_t)m * CIN + half * 8;
#pragma unroll
  for (int ch = 0; ch < 12; ++ch) {
    bf16x8 a = *(const bf16x8*)(Arow + ch * 32);
#pragma unroll
    for (int t = 0; t < 12; ++t) {
      bf16x8 b = *(const bf16x8*)(Bbase + (size_t)(16 * t) * CIN + ch * 32);
      acc[t] = __builtin_amdgcn_mfma_f32_16x16x32_bf16(a, b, acc[t], 0, 0, 0);
    }
  }

  // ---- Epilogue: D layout col=lane&15, row=(lane>>4)*4+reg ----
  const int r0 = blk * 64 + 16 * w + half * 4;
#pragma unroll
  for (int t = 0; t < 12; ++t) {
    float bv = b2[16 * t + m];
#pragma unroll
    for (int reg = 0; reg < 4; ++reg)
      h[(size_t)(r0 + reg) * COUT + 16 * t + m] = acc[t][reg] + bv;
  }
}

// ---------------------------------------------------------------------------
// K2a: partial 3-NN over one src segment per block.
// R3: back to the measured-good R0 skeleton (NDST=1, 1024 blocks = 4
// waves/SIMD, per-point broadcast LDS reads) with ONE change: the top-3
// insert is now BRANCHLESS (3 v_cmp + 10 v_cndmask per point, zero branches,
// zero divergence). Semantics verified identical to the strict-< ascending
// scan (ties keep earliest index, matching jax.lax.top_k).
// Partials stored segment-major so each block writes contiguous lines.
// ---------------------------------------------------------------------------
__device__ __forceinline__ float dist2_rn(float px, float py, float pz,
                                          float sx, float sy, float sz)
{
  float dx = __fsub_rn(px, sx);
  float dy = __fsub_rn(py, sy);
  float dz = __fsub_rn(pz, sz);
  return __fadd_rn(__fadd_rn(__fmul_rn(dx, dx), __fmul_rn(dy, dy)),
                   __fmul_rn(dz, dz));
}

__global__ __launch_bounds__(256) void k2a_knn_part(
    const float* __restrict__ xyz, const float* __restrict__ sxyz,
    float* __restrict__ pd2, int* __restrict__ pj)
{
  __shared__ __align__(16) float lds[SEGLEN * 3];
  const int tid  = threadIdx.x;
  const int dgrp = blockIdx.x >> 2;          // 256-dst group (0..255)
  const int seg  = blockIdx.x & 3;
  const int b    = dgrp >> 6;                // 64 groups per batch segment
  const float* src = xyz + ((size_t)b * N_C + (size_t)seg * SEGLEN) * 3;
  {
    const float4* s4 = (const float4*)src;
    float4* d4 = (float4*)lds;
#pragma unroll
    for (int i = 0; i < 3; ++i) d4[tid + 256 * i] = s4[tid + 256 * i];
  }
  const int dst = dgrp * 256 + tid;
  float px = sxyz[(size_t)dst * 3 + 0];
  float py = sxyz[(size_t)dst * 3 + 1];
  float pz = sxyz[(size_t)dst * 3 + 2];
  __syncthreads();

  float t0 = 1e30f, t1 = 1e30f, t2 = 1e30f;
  int   j0 = -1, j1 = -1, j2 = -1;
#pragma unroll 8
  for (int j = 0; j < SEGLEN; ++j) {
    float sx = lds[3 * j + 0];
    float sy = lds[3 * j + 1];
    float sz = lds[3 * j + 2];
    float d = dist2_rn(px, py, pz, sx, sy, sz);
    // branchless strict-< insert (old values on all RHS, update t2->t1->t0)
    bool c2 = d < t2, c1 = d < t1, c0 = d < t0;
    t2 = c1 ? t1 : (c2 ? d : t2);  j2 = c1 ? j1 : (c2 ? j : j2);
    t1 = c0 ? t0 : (c1 ? d : t1);  j1 = c0 ? j0 : (c1 ? j : j1);
    t0 = c0 ? d  : t0;             j0 = c0 ? j  : j0;
  }

  const int jb = b * N_C + seg * SEGLEN;
  const size_t o = ((size_t)seg * MF + dst) * 4;   // segment-major: contiguous
  *(float4*)(pd2 + o) = make_float4(t0, t1, t2, 1e30f);
  *(int4*)(pj + o)    = make_int4(jb + j0, jb + j1, jb + j2, 0x7fffffff);
}

// ---------------------------------------------------------------------------
// K2b: merge partial lists -> final top-3 + weights (segment-major reads).
// ---------------------------------------------------------------------------
__global__ __launch_bounds__(256) void k2b_knn_merge(
    const float* __restrict__ pd2, const int* __restrict__ pj,
    int* __restrict__ knn_i, float* __restrict__ knn_w)
{
  const int dst = blockIdx.x * 256 + threadIdx.x;
  float t0 = 1e30f, t1 = 1e30f, t2 = 1e30f;
  int   j0 = 0x7fffffff, j1 = 0x7fffffff, j2 = 0x7fffffff;
#pragma unroll
  for (int s = 0; s < 4; ++s) {
    const size_t o = ((size_t)s * MF + dst) * 4;
    float4 d4 = *(const float4*)(pd2 + o);
    int4   i4 = *(const int4*)(pj + o);
    float dc[4] = {d4.x, d4.y, d4.z, d4.w};
    int   ic[4] = {i4.x, i4.y, i4.z, i4.w};
#pragma unroll
    for (int k = 0; k < 4; ++k) {
      float d = dc[k]; int j = ic[k];
      bool lt2 = (d < t2) || (d == t2 && j < j2);
      if (lt2) {
        bool lt1 = (d < t1) || (d == t1 && j < j1);
        if (lt1) {
          t2 = t1; j2 = j1;
          bool lt0 = (d < t0) || (d == t0 && j < j0);
          if (lt0) { t1 = t0; j1 = j0; t0 = d; j0 = j; }
          else     { t1 = d; j1 = j; }
        } else { t2 = d; j2 = j; }
      }
    }
  }
  float d0 = sqrtf(t0), d1 = sqrtf(t1), d2s = sqrtf(t2);
  float r0 = 1.f / (d0 + 1e-8f);
  float r1 = 1.f / (d1 + 1e-8f);
  float r2 = 1.f / (d2s + 1e-8f);
  float inv = 1.f / (r0 + r1 + r2);
  knn_i[(size_t)dst * 3 + 0] = j0;
  knn_i[(size_t)dst * 3 + 1] = j1;
  knn_i[(size_t)dst * 3 + 2] = j2;
  knn_w[(size_t)dst * 3 + 0] = r0 * inv;
  knn_w[(size_t)dst * 3 + 1] = r1 * inv;
  knn_w[(size_t)dst * 3 + 2] = r2 * inv;
}

// ---------------------------------------------------------------------------
// K3: out = LN(support_feats) @ w1 + b1 + interp(h)   [65536 x 192] x [192 x 192]
// MFMA structure as K1 (K=192 -> 6 chunks). Epilogue stages acc+bias into an
// LDS tile (union-overlaid with the bf16 A-tile), then a float4-vectorized
// pass does the 3-NN gather + store.
// ---------------------------------------------------------------------------
__global__ __launch_bounds__(256) void k3_ln_gemm_interp(
    const float* __restrict__ sfeats, const float* __restrict__ ln_g,
    const float* __restrict__ ln_b, const __bf16* __restrict__ wt1,
    const float* __restrict__ b1, const float* __restrict__ h,
    const int* __restrict__ knn_i, const float* __restrict__ knn_w,
    float* __restrict__ out)
{
  union SMem {
    __bf16 a[64][COUT + 8];    // 25.6 KB — LN'd A-tile (phases 1-2)
    float  c[64][COUT + 4];    // 50.2 KB — staged GEMM result (epilogue)
  };
  __shared__ __align__(16) SMem sm;
  const int tid = threadIdx.x;
  const int blk = blockIdx.x;

  // ---- Phase 1: LN (4 threads/row, 12 float4 each) ----
  {
    const int r = tid >> 2, q = tid & 3;
    const float* frow = sfeats + (size_t)(blk * 64 + r) * COUT;
    float4 v[12];
    float sum = 0.f, sumsq = 0.f;
#pragma unroll
    for (int i = 0; i < 12; ++i) {
      float4 t = *(const float4*)(frow + (q + 4 * i) * 4);
      v[i] = t;
      sum   += (t.x + t.y) + (t.z + t.w);
      sumsq += (t.x * t.x + t.y * t.y) + (t.z * t.z + t.w * t.w);
    }
    sum   += __shfl_xor(sum, 1);  sumsq += __shfl_xor(sumsq, 1);
    sum   += __shfl_xor(sum, 2);  sumsq += __shfl_xor(sumsq, 2);
    float mean = sum * (1.f / COUT);
    float var  = sumsq * (1.f / COUT) - mean * mean;
    if (var < 0.f) var = 0.f;
    float rs = rsqrtf(var + LN_EPS);
#pragma unroll
    for (int i = 0; i < 12; ++i) {
      float4 g4 = *(const float4*)(ln_g + (q + 4 * i) * 4);
      float4 b4 = *(const float4*)(ln_b + (q + 4 * i) * 4);
      bf16x4 o;
      o[0] = (__bf16)((v[i].x - mean) * rs * g4.x + b4.x);
      o[1] = (__bf16)((v[i].y - mean) * rs * g4.y + b4.y);
      o[2] = (__bf16)((v[i].z - mean) * rs * g4.z + b4.z);
      o[3] = (__bf16)((v[i].w - mean) * rs * g4.w + b4.w);
      *(bf16x4*)&sm.a[r][(q + 4 * i) * 4] = o;
    }
  }
  __syncthreads();

  // ---- Phase 2: MFMA ----
  const int w = tid >> 6, lane = tid & 63, m = lane & 15, half = lane >> 4;
  f32x4 acc[12];
#pragma unroll
  for (int t = 0; t < 12; ++t) acc[t] = (f32x4){0.f, 0.f, 0.f, 0.f};

  const __bf16* Arow = &sm.a[16 * w + m][half * 8];
  const __bf16* Bbase = wt1 + (size_t)m * COUT + half * 8;
#pragma unroll
  for (int ch = 0; ch < 6; ++ch) {
    bf16x8 a = *(const bf16x8*)(Arow + ch * 32);
#pragma unroll
    for (int t = 0; t < 12; ++t) {
      bf16x8 b = *(const bf16x8*)(Bbase + (size_t)(16 * t) * COUT + ch * 32);
      acc[t] = __builtin_amdgcn_mfma_f32_16x16x32_bf16(a, b, acc[t], 0, 0, 0);
    }
  }

  // ---- Stage acc+bias into LDS (all waves must be done reading sm.a) ----
  float bv[12];
#pragma unroll
  for (int t = 0; t < 12; ++t) bv[t] = b1[16 * t + m];
  __syncthreads();
  {
    const int rr = 16 * w + half * 4;
#pragma unroll
    for (int t = 0; t < 12; ++t)
#pragma unroll
      for (int reg = 0; reg < 4; ++reg)
        sm.c[rr + reg][16 * t + m] = acc[t][reg] + bv[t];
  }
  __syncthreads();

  // ---- Vectorized interp + store: 4 threads per row, float4 everywhere ----
  {
    const int r = tid >> 2, q = tid & 3;
    const int R = blk * 64 + r;
    int   i0 = knn_i[(size_t)R * 3 + 0];
    int   i1 = knn_i[(size_t)R * 3 + 1];
    int   i2 = knn_i[(size_t)R * 3 + 2];
    float w0 = knn_w[(size_t)R * 3 + 0];
    float w1v = knn_w[(size_t)R * 3 + 1];
    float w2v = knn_w[(size_t)R * 3 + 2];
    const float* h0 = h + (size_t)i0 * COUT;
    const float* h1 = h + (size_t)i1 * COUT;
    const float* h2 = h + (size_t)i2 * COUT;
    float* orow = out + (size_t)R * COUT;
#pragma unroll
    for (int i = 0; i < 12; ++i) {
      const int col = 16 * i + 4 * q;
      f32x4 cv = *(const f32x4*)&sm.c[r][col];
      f32x4 g0 = *(const f32x4*)(h0 + col);
      f32x4 g1 = *(const f32x4*)(h1 + col);
      f32x4 g2 = *(const f32x4*)(h2 + col);
      f32x4 o  = cv + w0 * g0 + w1v * g1 + w2v * g2;
      *(f32x4*)(orow + col) = o;
    }
  }
}

// ---------------------------------------------------------------------------
// K4: passthrough outputs — support_xyz copy + support_offset as float
// ---------------------------------------------------------------------------
__global__ __launch_bounds__(256) void k4_tail(
    const float* __restrict__ sxyz, const int* __restrict__ soff,
    float* __restrict__ out_tail)
{
  const int t = blockIdx.x * 256 + threadIdx.x;
  if (t < MF * 3) out_tail[t] = sxyz[t];
  if (t < B_SEG) out_tail[MF * 3 + t] = (float)soff[t];
}

// ---------------------------------------------------------------------------
extern "C" void kernel_launch(void* const* d_in, const int* in_sizes, int n_in,
                              void* d_out, int out_size, void* d_ws, size_t ws_size,
                              hipStream_t stream)
{
  const float* feats  = (const float*)d_in[0];
  const float* xyz    = (const float*)d_in[1];
  const float* sxyz   = (const float*)d_in[2];
  const float* sfeats = (const float*)d_in[3];
  const int*   soff   = (const int*)d_in[5];
  const float* ln1_g  = (const float*)d_in[6];
  const float* ln1_b  = (const float*)d_in[7];
  const float* w1     = (const float*)d_in[8];
  const float* b1     = (const float*)d_in[9];
  const float* ln2_g  = (const float*)d_in[10];
  const float* ln2_b  = (const float*)d_in[11];
  const float* w2     = (const float*)d_in[12];
  const float* b2     = (const float*)d_in[13];
  float* out = (float*)d_out;

  // workspace layout
  float*  h     = (float*)d_ws;                      // 16384*192 f32 (12.6 MB)
  int*    knn_i = (int*)(h + (size_t)MT * COUT);     // 65536*3 ints
  float*  knn_w = (float*)(knn_i + (size_t)MF * 3);  // 65536*3 floats
  float*  pd2   = knn_w + (size_t)MF * 3;            // 4 segs * 65536 * 4 floats (4 MB)
  int*    pj    = (int*)(pd2 + (size_t)MF * 16);     // 4 segs * 65536 * 4 ints   (4 MB)
  __bf16* wt2   = (__bf16*)(pj + (size_t)MF * 16);   // 192*384 bf16
  __bf16* wt1   = wt2 + (size_t)COUT * CIN;          // 192*192 bf16

  k0_prep<<<(CIN * COUT + COUT * COUT) / 256, 256, 0, stream>>>(w2, w1, wt2, wt1);
  k1_ln_gemm<<<MT / 64, 256, 0, stream>>>(feats, ln2_g, ln2_b, wt2, b2, h);
  k2a_knn_part<<<(MF / 256) * NSEG, 256, 0, stream>>>(xyz, sxyz, pd2, pj);
  k2b_knn_merge<<<MF / 256, 256, 0, stream>>>(pd2, pj, knn_i, knn_w);
  k3_ln_gemm_interp<<<MF / 64, 256, 0, stream>>>(sfeats, ln1_g, ln1_b, wt1, b1,
                                                 h, knn_i, knn_w, out);
  k4_tail<<<(MF * 3) / 256, 256, 0, stream>>>(sxyz, soff, out + (size_t)MF * COUT);
}

// Round 5
// 318.490 us; speedup vs baseline: 2.2838x; 1.0936x over previous
//
#include <hip/hip_runtime.h>
#include <cstddef>
#include <cstdint>

// Problem constants (fixed by setup_inputs)
constexpr int B_SEG   = 4;
constexpr int N_C     = 4096;    // coarse points per batch
constexpr int M_F     = 16384;   // fine points per batch
constexpr int CIN     = 384;
constexpr int COUT    = 192;
constexpr int MT      = B_SEG * N_C;   // 16384 coarse rows
constexpr int MF      = B_SEG * M_F;   // 65536 fine rows
constexpr float LN_EPS = 1e-5f;

constexpr int GRES    = 16;            // KNN grid resolution (16^3 cells/batch)
constexpr int NCELL   = GRES * GRES * GRES;   // 4096

typedef __bf16 bf16x8 __attribute__((ext_vector_type(8)));
typedef __bf16 bf16x4 __attribute__((ext_vector_type(4)));
typedef float  f32x4  __attribute__((ext_vector_type(4)));

// ---------------------------------------------------------------------------
// K0: one-time prep — transpose+convert weights to bf16 [n][k] layout so the
// GEMM kernels load B-fragments as contiguous 16B global reads.
// ---------------------------------------------------------------------------
__global__ __launch_bounds__(256) void k0_prep(
    const float* __restrict__ w2, const float* __restrict__ w1,
    __bf16* __restrict__ wt2, __bf16* __restrict__ wt1)
{
  int e = blockIdx.x * 256 + threadIdx.x;
  if (e < CIN * COUT) {                       // w2: [384][192] -> wt2 [192][384]
    int k = e / COUT, n = e % COUT;
    wt2[(size_t)n * CIN + k] = (__bf16)w2[e];
  }
  e -= CIN * COUT;
  if (e >= 0 && e < COUT * COUT) {            // w1: [192][192] -> wt1 [192][192]
    int k = e / COUT, n = e % COUT;
    wt1[(size_t)n * COUT + k] = (__bf16)w1[e];
  }
}

// ---------------------------------------------------------------------------
// K1: h = LN(feats) @ w2 + b2      [16384 x 384] x [384 x 192]
// ---------------------------------------------------------------------------
__global__ __launch_bounds__(256) void k1_ln_gemm(
    const float* __restrict__ feats, const float* __restrict__ ln_g,
    const float* __restrict__ ln_b, const __bf16* __restrict__ wt2,
    const float* __restrict__ b2, float* __restrict__ h)
{
  __shared__ __align__(16) __bf16 As[64][CIN + 8];
  const int tid = threadIdx.x;
  const int blk = blockIdx.x;

  // ---- Phase 1: LN (4 threads/row, 24 float4 each) ----
  {
    const int r = tid >> 2, q = tid & 3;
    const float* frow = feats + (size_t)(blk * 64 + r) * CIN;
    float4 v[24];
    float sum = 0.f, sumsq = 0.f;
#pragma unroll
    for (int i = 0; i < 24; ++i) {
      float4 t = *(const float4*)(frow + (q + 4 * i) * 4);
      v[i] = t;
      sum   += (t.x + t.y) + (t.z + t.w);
      sumsq += (t.x * t.x + t.y * t.y) + (t.z * t.z + t.w * t.w);
    }
    sum   += __shfl_xor(sum, 1);  sumsq += __shfl_xor(sumsq, 1);
    sum   += __shfl_xor(sum, 2);  sumsq += __shfl_xor(sumsq, 2);
    float mean = sum * (1.f / CIN);
    float var  = sumsq * (1.f / CIN) - mean * mean;
    if (var < 0.f) var = 0.f;
    float rs = rsqrtf(var + LN_EPS);
#pragma unroll
    for (int i = 0; i < 24; ++i) {
      float4 g4 = *(const float4*)(ln_g + (q + 4 * i) * 4);
      float4 b4 = *(const float4*)(ln_b + (q + 4 * i) * 4);
      bf16x4 o;
      o[0] = (__bf16)((v[i].x - mean) * rs * g4.x + b4.x);
      o[1] = (__bf16)((v[i].y - mean) * rs * g4.y + b4.y);
      o[2] = (__bf16)((v[i].z - mean) * rs * g4.z + b4.z);
      o[3] = (__bf16)((v[i].w - mean) * rs * g4.w + b4.w);
      *(bf16x4*)&As[r][(q + 4 * i) * 4] = o;
    }
  }
  __syncthreads();

  // ---- Phase 2: MFMA ----
  const int w = tid >> 6, lane = tid & 63, m = lane & 15, half = lane >> 4;
  f32x4 acc[12];
#pragma unroll
  for (int t = 0; t < 12; ++t) acc[t] = (f32x4){0.f, 0.f, 0.f, 0.f};

  const __bf16* Arow = &As[16 * w + m][half * 8];
  const __bf16* Bbase = wt2 + (size_t)m * CIN + half * 8;
#pragma unroll
  for (int ch = 0; ch < 12; ++ch) {
    bf16x8 a = *(const bf16x8*)(Arow + ch * 32);
#pragma unroll
    for (int t = 0; t < 12; ++t) {
      bf16x8 b = *(const bf16x8*)(Bbase + (size_t)(16 * t) * CIN + ch * 32);
      acc[t] = __builtin_amdgcn_mfma_f32_16x16x32_bf16(a, b, acc[t], 0, 0, 0);
    }
  }

  // ---- Epilogue: D layout col=lane&15, row=(lane>>4)*4+reg ----
  const int r0 = blk * 64 + 16 * w + half * 4;
#pragma unroll
  for (int t = 0; t < 12; ++t) {
    float bv = b2[16 * t + m];
#pragma unroll
    for (int reg = 0; reg < 4; ++reg)
      h[(size_t)(r0 + reg) * COUT + 16 * t + m] = acc[t][reg] + bv;
  }
}

// ---------------------------------------------------------------------------
// KNN helpers: exact-rounding distance (same op chain as the passing R3
// version) — selection key is (d2_bits << 32) | idx, compared as u64, which
// is lexicographic (d2, idx): exactly jax.lax.top_k's stable ordering, and
// order-independent (so nondeterministic within-cell build order is fine).
// ---------------------------------------------------------------------------
__device__ __forceinline__ float dist2_rn(float px, float py, float pz,
                                          float sx, float sy, float sz)
{
  float dx = __fsub_rn(px, sx);
  float dy = __fsub_rn(py, sy);
  float dz = __fsub_rn(pz, sz);
  return __fadd_rn(__fadd_rn(__fmul_rn(dx, dx), __fmul_rn(dy, dy)),
                   __fmul_rn(dz, dz));
}

// ---------------------------------------------------------------------------
// KG: grid build — one block per batch. LDS histogram over 16^3 cells,
// exclusive scan, then counting-sort scatter of float4(x,y,z,id_bits) into a
// cell-sorted AoS array in workspace. 4096 points per block.
// ---------------------------------------------------------------------------
__global__ __launch_bounds__(256) void kgrid(
    const float* __restrict__ xyz,
    float4* __restrict__ pts_g, uint32_t* __restrict__ starts_g)
{
  __shared__ uint32_t cnt[NCELL];
  __shared__ uint32_t bsum[256];
  const int t = threadIdx.x;
  const int b = blockIdx.x;
  const float* src = xyz + (size_t)b * N_C * 3;

#pragma unroll
  for (int i = 0; i < NCELL / 256; ++i) cnt[t + 256 * i] = 0u;
  __syncthreads();

  int   cl[16];
  float xr[16], yr[16], zr[16];
#pragma unroll
  for (int i = 0; i < 16; ++i) {
    int p = i * 256 + t;
    float x = src[3 * p + 0], y = src[3 * p + 1], z = src[3 * p + 2];
    xr[i] = x; yr[i] = y; zr[i] = z;
    int ix = min(GRES - 1, max(0, (int)(x * (float)GRES)));
    int iy = min(GRES - 1, max(0, (int)(y * (float)GRES)));
    int iz = min(GRES - 1, max(0, (int)(z * (float)GRES)));
    int c = (ix << 8) | (iy << 4) | iz;
    cl[i] = c;
    atomicAdd(&cnt[c], 1u);
  }
  __syncthreads();

  // exclusive scan of cnt[4096]: per-thread 16-seq + Hillis-Steele over 256
  uint32_t loc[16], s = 0;
#pragma unroll
  for (int j = 0; j < 16; ++j) { loc[j] = cnt[t * 16 + j]; s += loc[j]; }
  bsum[t] = s;
  __syncthreads();
  for (int off = 1; off < 256; off <<= 1) {
    uint32_t v = (t >= off) ? bsum[t - off] : 0u;
    __syncthreads();
    bsum[t] += v;
    __syncthreads();
  }
  uint32_t run = bsum[t] - s;          // exclusive block offset
#pragma unroll
  for (int j = 0; j < 16; ++j) { cnt[t * 16 + j] = run; run += loc[j]; }
  __syncthreads();

  // dump starts to global (before cnt is mutated by the scatter cursors)
#pragma unroll
  for (int i = 0; i < NCELL / 256; ++i)
    starts_g[(size_t)b * (NCELL + 1) + t + 256 * i] = cnt[t + 256 * i];
  if (t == 0) starts_g[(size_t)b * (NCELL + 1) + NCELL] = N_C;
  __syncthreads();

  // counting-sort scatter (within-cell order nondeterministic — OK, the
  // search comparator is order-independent)
#pragma unroll
  for (int i = 0; i < 16; ++i) {
    int p = i * 256 + t;
    uint32_t pos = atomicAdd(&cnt[cl[i]], 1u);
    size_t o = (size_t)b * N_C + pos;
    pts_g[o] = make_float4(xr[i], yr[i], zr[i], __uint_as_float((uint32_t)p));
  }
}

// ---------------------------------------------------------------------------
// KNN search: one query per thread, 256 blocks (64/batch). Only the 16 KB
// cell-start table lives in LDS; candidate points are gathered from the
// cell-sorted AoS array in global (64 KB/batch -> L2-hot, one 16B load per
// candidate). Expanding-shell scan:
//   shells 0..1 (27 cells) unconditionally, then shells R>=2 until
//   t2 < (R*h)^2 * (1-1e-6)   (conservative: unscanned cells are >= R*h away)
// Inserts use the u64 (d2,idx) key -> bit-exact vs reference incl. ties.
// Emits final knn_i / knn_w directly.
// ---------------------------------------------------------------------------
__global__ __launch_bounds__(256) void kknn(
    const float* __restrict__ sxyz,
    const float4* __restrict__ pts_g, const uint32_t* __restrict__ starts_g,
    int* __restrict__ knn_i, float* __restrict__ knn_w)
{
  __shared__ uint32_t starts[NCELL + 1];
  const int tid = threadIdx.x;
  const int blk = blockIdx.x;
  const int b   = blk >> 6;                 // 64 blocks per batch

#pragma unroll
  for (int i = 0; i < 17; ++i) {
    int k = tid + 256 * i;
    if (k < NCELL + 1) starts[k] = starts_g[(size_t)b * (NCELL + 1) + k];
  }

  const float4* pb = pts_g + (size_t)b * N_C;
  const int dst = blk * 256 + tid;
  const float px = sxyz[(size_t)dst * 3 + 0];
  const float py = sxyz[(size_t)dst * 3 + 1];
  const float pz = sxyz[(size_t)dst * 3 + 2];
  const int cx = min(GRES - 1, max(0, (int)(px * (float)GRES)));
  const int cy = min(GRES - 1, max(0, (int)(py * (float)GRES)));
  const int cz = min(GRES - 1, max(0, (int)(pz * (float)GRES)));
  __syncthreads();

  unsigned long long bk0 = ~0ull, bk1 = ~0ull, bk2 = ~0ull;

  // shells 0..1: 3x3x3 box around the query cell
  for (int xx = cx - 1; xx <= cx + 1; ++xx) {
    if ((unsigned)xx > (unsigned)(GRES - 1)) continue;
    for (int yy = cy - 1; yy <= cy + 1; ++yy) {
      if ((unsigned)yy > (unsigned)(GRES - 1)) continue;
      for (int zz = cz - 1; zz <= cz + 1; ++zz) {
        if ((unsigned)zz > (unsigned)(GRES - 1)) continue;
        int c = (xx << 8) | (yy << 4) | zz;
        for (uint32_t i = starts[c], e = starts[c + 1]; i < e; ++i) {
          float4 p4 = pb[i];
          float d2 = dist2_rn(px, py, pz, p4.x, p4.y, p4.z);
          unsigned long long key =
              ((unsigned long long)__float_as_uint(d2) << 32) |
              (unsigned long long)__float_as_uint(p4.w);
          bool i0 = key < bk0, i1 = key < bk1, i2 = key < bk2;
          bk2 = i1 ? bk1 : (i2 ? key : bk2);
          bk1 = i0 ? bk0 : (i1 ? key : bk1);
          bk0 = i0 ? key : bk0;
        }
      }
    }
  }

  const float H = 1.0f / (float)GRES;
  float t2f = __uint_as_float((uint32_t)(bk2 >> 32));   // NaN while <3 found
  if (!(t2f < H * H * 0.999999f)) {
    for (int R = 2; R <= GRES - 1; ++R) {
      int x0 = max(cx - R, 0), x1 = min(cx + R, GRES - 1);
      int y0 = max(cy - R, 0), y1 = min(cy + R, GRES - 1);
      int z0 = max(cz - R, 0), z1 = min(cz + R, GRES - 1);
      for (int xx = x0; xx <= x1; ++xx) {
        int ax = abs(xx - cx);
        for (int yy = y0; yy <= y1; ++yy) {
          int ay = abs(yy - cy);
          for (int zz = z0; zz <= z1; ++zz) {
            int ch = max(ax, max(ay, abs(zz - cz)));
            if (ch != R) continue;                     // shell only
            int c = (xx << 8) | (yy << 4) | zz;
            for (uint32_t i = starts[c], e = starts[c + 1]; i < e; ++i) {
              float4 p4 = pb[i];
              float d2 = dist2_rn(px, py, pz, p4.x, p4.y, p4.z);
              unsigned long long key =
                  ((unsigned long long)__float_as_uint(d2) << 32) |
                  (unsigned long long)__float_as_uint(p4.w);
              bool i0 = key < bk0, i1 = key < bk1, i2 = key < bk2;
              bk2 = i1 ? bk1 : (i2 ? key : bk2);
              bk1 = i0 ? bk0 : (i1 ? key : bk1);
              bk0 = i0 ? key : bk0;
            }
          }
        }
      }
      t2f = __uint_as_float((uint32_t)(bk2 >> 32));
      float thr = (float)R * H;
      if (t2f < thr * thr * 0.999999f) break;
    }
  }

  // weights (identical arithmetic to the passing R3 merge kernel)
  float d0  = sqrtf(__uint_as_float((uint32_t)(bk0 >> 32)));
  float d1  = sqrtf(__uint_as_float((uint32_t)(bk1 >> 32)));
  float d2s = sqrtf(__uint_as_float((uint32_t)(bk2 >> 32)));
  float r0 = 1.f / (d0 + 1e-8f);
  float r1 = 1.f / (d1 + 1e-8f);
  float r2 = 1.f / (d2s + 1e-8f);
  float inv = 1.f / (r0 + r1 + r2);
  const int jb = b * N_C;
  knn_i[(size_t)dst * 3 + 0] = jb + (int)(bk0 & 0xffffffffull);
  knn_i[(size_t)dst * 3 + 1] = jb + (int)(bk1 & 0xffffffffull);
  knn_i[(size_t)dst * 3 + 2] = jb + (int)(bk2 & 0xffffffffull);
  knn_w[(size_t)dst * 3 + 0] = r0 * inv;
  knn_w[(size_t)dst * 3 + 1] = r1 * inv;
  knn_w[(size_t)dst * 3 + 2] = r2 * inv;
}

// ---------------------------------------------------------------------------
// K3: out = LN(support_feats) @ w1 + b1 + interp(h)   [65536 x 192] x [192 x 192]
// ---------------------------------------------------------------------------
__global__ __launch_bounds__(256) void k3_ln_gemm_interp(
    const float* __restrict__ sfeats, const float* __restrict__ ln_g,
    const float* __restrict__ ln_b, const __bf16* __restrict__ wt1,
    const float* __restrict__ b1, const float* __restrict__ h,
    const int* __restrict__ knn_i, const float* __restrict__ knn_w,
    float* __restrict__ out)
{
  union SMem {
    __bf16 a[64][COUT + 8];    // 25.6 KB — LN'd A-tile (phases 1-2)
    float  c[64][COUT + 4];    // 50.2 KB — staged GEMM result (epilogue)
  };
  __shared__ __align__(16) SMem sm;
  const int tid = threadIdx.x;
  const int blk = blockIdx.x;

  // ---- Phase 1: LN (4 threads/row, 12 float4 each) ----
  {
    const int r = tid >> 2, q = tid & 3;
    const float* frow = sfeats + (size_t)(blk * 64 + r) * COUT;
    float4 v[12];
    float sum = 0.f, sumsq = 0.f;
#pragma unroll
    for (int i = 0; i < 12; ++i) {
      float4 t = *(const float4*)(frow + (q + 4 * i) * 4);
      v[i] = t;
      sum   += (t.x + t.y) + (t.z + t.w);
      sumsq += (t.x * t.x + t.y * t.y) + (t.z * t.z + t.w * t.w);
    }
    sum   += __shfl_xor(sum, 1);  sumsq += __shfl_xor(sumsq, 1);
    sum   += __shfl_xor(sum, 2);  sumsq += __shfl_xor(sumsq, 2);
    float mean = sum * (1.f / COUT);
    float var  = sumsq * (1.f / COUT) - mean * mean;
    if (var < 0.f) var = 0.f;
    float rs = rsqrtf(var + LN_EPS);
#pragma unroll
    for (int i = 0; i < 12; ++i) {
      float4 g4 = *(const float4*)(ln_g + (q + 4 * i) * 4);
      float4 b4 = *(const float4*)(ln_b + (q + 4 * i) * 4);
      bf16x4 o;
      o[0] = (__bf16)((v[i].x - mean) * rs * g4.x + b4.x);
      o[1] = (__bf16)((v[i].y - mean) * rs * g4.y + b4.y);
      o[2] = (__bf16)((v[i].z - mean) * rs * g4.z + b4.z);
      o[3] = (__bf16)((v[i].w - mean) * rs * g4.w + b4.w);
      *(bf16x4*)&sm.a[r][(q + 4 * i) * 4] = o;
    }
  }
  __syncthreads();

  // ---- Phase 2: MFMA ----
  const int w = tid >> 6, lane = tid & 63, m = lane & 15, half = lane >> 4;
  f32x4 acc[12];
#pragma unroll
  for (int t = 0; t < 12; ++t) acc[t] = (f32x4){0.f, 0.f, 0.f, 0.f};

  const __bf16* Arow = &sm.a[16 * w + m][half * 8];
  const __bf16* Bbase = wt1 + (size_t)m * COUT + half * 8;
#pragma unroll
  for (int ch = 0; ch < 6; ++ch) {
    bf16x8 a = *(const bf16x8*)(Arow + ch * 32);
#pragma unroll
    for (int t = 0; t < 12; ++t) {
      bf16x8 b = *(const bf16x8*)(Bbase + (size_t)(16 * t) * COUT + ch * 32);
      acc[t] = __builtin_amdgcn_mfma_f32_16x16x32_bf16(a, b, acc[t], 0, 0, 0);
    }
  }

  // ---- Stage acc+bias into LDS (all waves must be done reading sm.a) ----
  float bv[12];
#pragma unroll
  for (int t = 0; t < 12; ++t) bv[t] = b1[16 * t + m];
  __syncthreads();
  {
    const int rr = 16 * w + half * 4;
#pragma unroll
    for (int t = 0; t < 12; ++t)
#pragma unroll
      for (int reg = 0; reg < 4; ++reg)
        sm.c[rr + reg][16 * t + m] = acc[t][reg] + bv[t];
  }
  __syncthreads();

  // ---- Vectorized interp + store: 4 threads per row, float4 everywhere ----
  {
    const int r = tid >> 2, q = tid & 3;
    const int R = blk * 64 + r;
    int   i0 = knn_i[(size_t)R * 3 + 0];
    int   i1 = knn_i[(size_t)R * 3 + 1];
    int   i2 = knn_i[(size_t)R * 3 + 2];
    float w0 = knn_w[(size_t)R * 3 + 0];
    float w1v = knn_w[(size_t)R * 3 + 1];
    float w2v = knn_w[(size_t)R * 3 + 2];
    const float* h0 = h + (size_t)i0 * COUT;
    const float* h1 = h + (size_t)i1 * COUT;
    const float* h2 = h + (size_t)i2 * COUT;
    float* orow = out + (size_t)R * COUT;
#pragma unroll
    for (int i = 0; i < 12; ++i) {
      const int col = 16 * i + 4 * q;
      f32x4 cv = *(const f32x4*)&sm.c[r][col];
      f32x4 g0 = *(const f32x4*)(h0 + col);
      f32x4 g1 = *(const f32x4*)(h1 + col);
      f32x4 g2 = *(const f32x4*)(h2 + col);
      f32x4 o  = cv + w0 * g0 + w1v * g1 + w2v * g2;
      *(f32x4*)(orow + col) = o;
    }
  }
}

// ---------------------------------------------------------------------------
// K4: passthrough outputs — support_xyz copy + support_offset as float
// ---------------------------------------------------------------------------
__global__ __launch_bounds__(256) void k4_tail(
    const float* __restrict__ sxyz, const int* __restrict__ soff,
    float* __restrict__ out_tail)
{
  const int t = blockIdx.x * 256 + threadIdx.x;
  if (t < MF * 3) out_tail[t] = sxyz[t];
  if (t < B_SEG) out_tail[MF * 3 + t] = (float)soff[t];
}

// ---------------------------------------------------------------------------
extern "C" void kernel_launch(void* const* d_in, const int* in_sizes, int n_in,
                              void* d_out, int out_size, void* d_ws, size_t ws_size,
                              hipStream_t stream)
{
  const float* feats  = (const float*)d_in[0];
  const float* xyz    = (const float*)d_in[1];
  const float* sxyz   = (const float*)d_in[2];
  const float* sfeats = (const float*)d_in[3];
  const int*   soff   = (const int*)d_in[5];
  const float* ln1_g  = (const float*)d_in[6];
  const float* ln1_b  = (const float*)d_in[7];
  const float* w1     = (const float*)d_in[8];
  const float* b1     = (const float*)d_in[9];
  const float* ln2_g  = (const float*)d_in[10];
  const float* ln2_b  = (const float*)d_in[11];
  const float* w2     = (const float*)d_in[12];
  const float* b2     = (const float*)d_in[13];
  float* out = (float*)d_out;

  // workspace layout (float units)
  float*    h       = (float*)d_ws;                        // 16384*192 f32
  int*      knn_i   = (int*)(h + (size_t)MT * COUT);       // 65536*3
  float*    knn_w   = (float*)(knn_i + (size_t)MF * 3);    // 65536*3
  float4*   pts_g   = (float4*)(knn_w + (size_t)MF * 3);   // 4*4096 float4
  uint32_t* starts_g= (uint32_t*)(pts_g + (size_t)B_SEG * N_C);   // 4*4097
  __bf16*   wt2     = (__bf16*)(starts_g + (size_t)B_SEG * (NCELL + 1));
  __bf16*   wt1     = wt2 + (size_t)COUT * CIN;

  k0_prep<<<(CIN * COUT + COUT * COUT) / 256, 256, 0, stream>>>(w2, w1, wt2, wt1);
  kgrid<<<B_SEG, 256, 0, stream>>>(xyz, pts_g, starts_g);
  k1_ln_gemm<<<MT / 64, 256, 0, stream>>>(feats, ln2_g, ln2_b, wt2, b2, h);
  kknn<<<MF / 256, 256, 0, stream>>>(sxyz, pts_g, starts_g, knn_i, knn_w);
  k3_ln_gemm_interp<<<MF / 64, 256, 0, stream>>>(sfeats, ln1_g, ln1_b, wt1, b1,
                                                 h, knn_i, knn_w, out);
  k4_tail<<<(MF * 3) / 256, 256, 0, stream>>>(sxyz, soff, out + (size_t)MF * COUT);
}

// Round 6
// 269.788 us; speedup vs baseline: 2.6961x; 1.1805x over previous
//
#include <hip/hip_runtime.h>
#include <cstddef>
#include <cstdint>

// Problem constants (fixed by setup_inputs)
constexpr int B_SEG   = 4;
constexpr int N_C     = 4096;    // coarse points per batch
constexpr int M_F     = 16384;   // fine points per batch
constexpr int CIN     = 384;
constexpr int COUT    = 192;
constexpr int MT      = B_SEG * N_C;   // 16384 coarse rows
constexpr int MF      = B_SEG * M_F;   // 65536 fine rows
constexpr float LN_EPS = 1e-5f;

constexpr int GRES    = 16;            // KNN grid resolution (16^3 cells/batch)
constexpr int NCELL   = GRES * GRES * GRES;   // 4096

typedef __bf16 bf16x8 __attribute__((ext_vector_type(8)));
typedef __bf16 bf16x4 __attribute__((ext_vector_type(4)));
typedef float  f32x4  __attribute__((ext_vector_type(4)));

// ---------------------------------------------------------------------------
// K0: one-time prep — transpose+convert weights to bf16 [n][k] layout so the
// GEMM kernels load B-fragments as contiguous 16B global reads.
// ---------------------------------------------------------------------------
__global__ __launch_bounds__(256) void k0_prep(
    const float* __restrict__ w2, const float* __restrict__ w1,
    __bf16* __restrict__ wt2, __bf16* __restrict__ wt1)
{
  int e = blockIdx.x * 256 + threadIdx.x;
  if (e < CIN * COUT) {                       // w2: [384][192] -> wt2 [192][384]
    int k = e / COUT, n = e % COUT;
    wt2[(size_t)n * CIN + k] = (__bf16)w2[e];
  }
  e -= CIN * COUT;
  if (e >= 0 && e < COUT * COUT) {            // w1: [192][192] -> wt1 [192][192]
    int k = e / COUT, n = e % COUT;
    wt1[(size_t)n * COUT + k] = (__bf16)w1[e];
  }
}

// ---------------------------------------------------------------------------
// K1: h = LN(feats) @ w2 + b2      [16384 x 384] x [384 x 192]
// ---------------------------------------------------------------------------
__global__ __launch_bounds__(256) void k1_ln_gemm(
    const float* __restrict__ feats, const float* __restrict__ ln_g,
    const float* __restrict__ ln_b, const __bf16* __restrict__ wt2,
    const float* __restrict__ b2, float* __restrict__ h)
{
  __shared__ __align__(16) __bf16 As[64][CIN + 8];
  const int tid = threadIdx.x;
  const int blk = blockIdx.x;

  // ---- Phase 1: LN (4 threads/row, 24 float4 each) ----
  {
    const int r = tid >> 2, q = tid & 3;
    const float* frow = feats + (size_t)(blk * 64 + r) * CIN;
    float4 v[24];
    float sum = 0.f, sumsq = 0.f;
#pragma unroll
    for (int i = 0; i < 24; ++i) {
      float4 t = *(const float4*)(frow + (q + 4 * i) * 4);
      v[i] = t;
      sum   += (t.x + t.y) + (t.z + t.w);
      sumsq += (t.x * t.x + t.y * t.y) + (t.z * t.z + t.w * t.w);
    }
    sum   += __shfl_xor(sum, 1);  sumsq += __shfl_xor(sumsq, 1);
    sum   += __shfl_xor(sum, 2);  sumsq += __shfl_xor(sumsq, 2);
    float mean = sum * (1.f / CIN);
    float var  = sumsq * (1.f / CIN) - mean * mean;
    if (var < 0.f) var = 0.f;
    float rs = rsqrtf(var + LN_EPS);
#pragma unroll
    for (int i = 0; i < 24; ++i) {
      float4 g4 = *(const float4*)(ln_g + (q + 4 * i) * 4);
      float4 b4 = *(const float4*)(ln_b + (q + 4 * i) * 4);
      bf16x4 o;
      o[0] = (__bf16)((v[i].x - mean) * rs * g4.x + b4.x);
      o[1] = (__bf16)((v[i].y - mean) * rs * g4.y + b4.y);
      o[2] = (__bf16)((v[i].z - mean) * rs * g4.z + b4.z);
      o[3] = (__bf16)((v[i].w - mean) * rs * g4.w + b4.w);
      *(bf16x4*)&As[r][(q + 4 * i) * 4] = o;
    }
  }
  __syncthreads();

  // ---- Phase 2: MFMA ----
  const int w = tid >> 6, lane = tid & 63, m = lane & 15, half = lane >> 4;
  f32x4 acc[12];
#pragma unroll
  for (int t = 0; t < 12; ++t) acc[t] = (f32x4){0.f, 0.f, 0.f, 0.f};

  const __bf16* Arow = &As[16 * w + m][half * 8];
  const __bf16* Bbase = wt2 + (size_t)m * CIN + half * 8;
#pragma unroll
  for (int ch = 0; ch < 12; ++ch) {
    bf16x8 a = *(const bf16x8*)(Arow + ch * 32);
#pragma unroll
    for (int t = 0; t < 12; ++t) {
      bf16x8 b = *(const bf16x8*)(Bbase + (size_t)(16 * t) * CIN + ch * 32);
      acc[t] = __builtin_amdgcn_mfma_f32_16x16x32_bf16(a, b, acc[t], 0, 0, 0);
    }
  }

  // ---- Epilogue: D layout col=lane&15, row=(lane>>4)*4+reg ----
  const int r0 = blk * 64 + 16 * w + half * 4;
#pragma unroll
  for (int t = 0; t < 12; ++t) {
    float bv = b2[16 * t + m];
#pragma unroll
    for (int reg = 0; reg < 4; ++reg)
      h[(size_t)(r0 + reg) * COUT + 16 * t + m] = acc[t][reg] + bv;
  }
}

// ---------------------------------------------------------------------------
// KNN helpers: exact-rounding distance; u64 key (d2_bits<<32)|idx compared
// lexicographically == jax.lax.top_k stable order; order-independent.
// ---------------------------------------------------------------------------
__device__ __forceinline__ float dist2_rn(float px, float py, float pz,
                                          float sx, float sy, float sz)
{
  float dx = __fsub_rn(px, sx);
  float dy = __fsub_rn(py, sy);
  float dz = __fsub_rn(pz, sz);
  return __fadd_rn(__fadd_rn(__fmul_rn(dx, dx), __fmul_rn(dy, dy)),
                   __fmul_rn(dz, dz));
}

// merge two sorted triples -> 3 smallest of the union (branchless 2-pointer)
__device__ __forceinline__ void merge3(
    unsigned long long& a0, unsigned long long& a1, unsigned long long& a2,
    unsigned long long b0, unsigned long long b1, unsigned long long b2)
{
  bool t = a0 <= b0;
  unsigned long long r0 = t ? a0 : b0;
  unsigned long long A0 = t ? a1 : a0;
  unsigned long long A1 = t ? a2 : a1;
  unsigned long long B0 = t ? b0 : b1;
  unsigned long long B1 = t ? b1 : b2;
  t = A0 <= B0;
  unsigned long long r1 = t ? A0 : B0;
  unsigned long long C0 = t ? A1 : A0;
  unsigned long long D0 = t ? B0 : B1;
  unsigned long long r2 = C0 <= D0 ? C0 : D0;
  a0 = r0; a1 = r1; a2 = r2;
}

// ---------------------------------------------------------------------------
// KG: grid build — one block per batch. LDS histogram over 16^3 cells,
// exclusive scan, then counting-sort scatter of float4(x,y,z,id_bits) into a
// cell-sorted AoS array in workspace. 4096 points per block.
// ---------------------------------------------------------------------------
__global__ __launch_bounds__(256) void kgrid(
    const float* __restrict__ xyz,
    float4* __restrict__ pts_g, uint32_t* __restrict__ starts_g)
{
  __shared__ uint32_t cnt[NCELL];
  __shared__ uint32_t bsum[256];
  const int t = threadIdx.x;
  const int b = blockIdx.x;
  const float* src = xyz + (size_t)b * N_C * 3;

#pragma unroll
  for (int i = 0; i < NCELL / 256; ++i) cnt[t + 256 * i] = 0u;
  __syncthreads();

  int   cl[16];
  float xr[16], yr[16], zr[16];
#pragma unroll
  for (int i = 0; i < 16; ++i) {
    int p = i * 256 + t;
    float x = src[3 * p + 0], y = src[3 * p + 1], z = src[3 * p + 2];
    xr[i] = x; yr[i] = y; zr[i] = z;
    int ix = min(GRES - 1, max(0, (int)(x * (float)GRES)));
    int iy = min(GRES - 1, max(0, (int)(y * (float)GRES)));
    int iz = min(GRES - 1, max(0, (int)(z * (float)GRES)));
    int c = (ix << 8) | (iy << 4) | iz;
    cl[i] = c;
    atomicAdd(&cnt[c], 1u);
  }
  __syncthreads();

  // exclusive scan of cnt[4096]: per-thread 16-seq + Hillis-Steele over 256
  uint32_t loc[16], s = 0;
#pragma unroll
  for (int j = 0; j < 16; ++j) { loc[j] = cnt[t * 16 + j]; s += loc[j]; }
  bsum[t] = s;
  __syncthreads();
  for (int off = 1; off < 256; off <<= 1) {
    uint32_t v = (t >= off) ? bsum[t - off] : 0u;
    __syncthreads();
    bsum[t] += v;
    __syncthreads();
  }
  uint32_t run = bsum[t] - s;          // exclusive block offset
#pragma unroll
  for (int j = 0; j < 16; ++j) { cnt[t * 16 + j] = run; run += loc[j]; }
  __syncthreads();

  // dump starts to global (before cnt is mutated by the scatter cursors)
#pragma unroll
  for (int i = 0; i < NCELL / 256; ++i)
    starts_g[(size_t)b * (NCELL + 1) + t + 256 * i] = cnt[t + 256 * i];
  if (t == 0) starts_g[(size_t)b * (NCELL + 1) + NCELL] = N_C;
  __syncthreads();

  // counting-sort scatter (within-cell order nondeterministic — OK, the
  // search comparator is order-independent)
#pragma unroll
  for (int i = 0; i < 16; ++i) {
    int p = i * 256 + t;
    uint32_t pos = atomicAdd(&cnt[cl[i]], 1u);
    size_t o = (size_t)b * N_C + pos;
    pts_g[o] = make_float4(xr[i], yr[i], zr[i], __uint_as_float((uint32_t)p));
  }
}

// ---------------------------------------------------------------------------
// KNN search v2: FOUR lanes per query (quad-parallel). 1024 blocks, 64
// queries/block -> 16 waves/CU (~50% occupancy) vs 8.6% in v1.
//  - all 4 lanes of a quad walk the SAME cells (uniform branching); each
//    strides the cell's candidate list by 4 (adjacent float4 loads = 64B
//    coalesced per quad)
//  - local sorted top-3 per lane; quad-wide top-3 via 2-level __shfl_xor
//    sorted-triple merge after the 27-cell box and after each ring (the
//    comparator is order-independent, so any partition is exact)
//  - ring stop rule unchanged: t2 < (R*h)^2*(1-1e-6), quad-uniform after
//    the merge
// ---------------------------------------------------------------------------
__global__ __launch_bounds__(256) void kknn(
    const float* __restrict__ sxyz,
    const float4* __restrict__ pts_g, const uint32_t* __restrict__ starts_g,
    int* __restrict__ knn_i, float* __restrict__ knn_w)
{
  __shared__ uint32_t starts[NCELL + 1];
  const int tid = threadIdx.x;
  const int blk = blockIdx.x;            // 1024 blocks, 256 per batch
  const int b   = blk >> 8;

#pragma unroll
  for (int i = 0; i < 17; ++i) {
    int k = tid + 256 * i;
    if (k < NCELL + 1) starts[k] = starts_g[(size_t)b * (NCELL + 1) + k];
  }

  const float4* pb = pts_g + (size_t)b * N_C;
  const int sub = tid & 3;
  const int dst = blk * 64 + (tid >> 2);
  const float px = sxyz[(size_t)dst * 3 + 0];
  const float py = sxyz[(size_t)dst * 3 + 1];
  const float pz = sxyz[(size_t)dst * 3 + 2];
  const int cx = min(GRES - 1, max(0, (int)(px * (float)GRES)));
  const int cy = min(GRES - 1, max(0, (int)(py * (float)GRES)));
  const int cz = min(GRES - 1, max(0, (int)(pz * (float)GRES)));
  __syncthreads();

  unsigned long long bk0 = ~0ull, bk1 = ~0ull, bk2 = ~0ull;

  // shells 0..1: 3x3x3 box around the query cell, strided by sub
  for (int xx = cx - 1; xx <= cx + 1; ++xx) {
    if ((unsigned)xx > (unsigned)(GRES - 1)) continue;
    for (int yy = cy - 1; yy <= cy + 1; ++yy) {
      if ((unsigned)yy > (unsigned)(GRES - 1)) continue;
      for (int zz = cz - 1; zz <= cz + 1; ++zz) {
        if ((unsigned)zz > (unsigned)(GRES - 1)) continue;
        int c = (xx << 8) | (yy << 4) | zz;
        for (uint32_t i = starts[c] + sub, e = starts[c + 1]; i < e; i += 4) {
          float4 p4 = pb[i];
          float d2 = dist2_rn(px, py, pz, p4.x, p4.y, p4.z);
          unsigned long long key =
              ((unsigned long long)__float_as_uint(d2) << 32) |
              (unsigned long long)__float_as_uint(p4.w);
          bool i0 = key < bk0, i1 = key < bk1, i2 = key < bk2;
          bk2 = i1 ? bk1 : (i2 ? key : bk2);
          bk1 = i0 ? bk0 : (i1 ? key : bk1);
          bk0 = i0 ? key : bk0;
        }
      }
    }
  }

  // quad-wide merge (lanes 4q..4q+3): xor 1 then xor 2
  merge3(bk0, bk1, bk2, __shfl_xor(bk0, 1), __shfl_xor(bk1, 1), __shfl_xor(bk2, 1));
  merge3(bk0, bk1, bk2, __shfl_xor(bk0, 2), __shfl_xor(bk1, 2), __shfl_xor(bk2, 2));

  const float H = 1.0f / (float)GRES;
  float t2f = __uint_as_float((uint32_t)(bk2 >> 32));   // NaN while <3 found
  if (!(t2f < H * H * 0.999999f)) {
    for (int R = 2; R <= GRES - 1; ++R) {
      int x0 = max(cx - R, 0), x1 = min(cx + R, GRES - 1);
      int y0 = max(cy - R, 0), y1 = min(cy + R, GRES - 1);
      int z0 = max(cz - R, 0), z1 = min(cz + R, GRES - 1);
      for (int xx = x0; xx <= x1; ++xx) {
        int ax = abs(xx - cx);
        for (int yy = y0; yy <= y1; ++yy) {
          int ay = abs(yy - cy);
          for (int zz = z0; zz <= z1; ++zz) {
            int ch = max(ax, max(ay, abs(zz - cz)));
            if (ch != R) continue;                     // shell only
            int c = (xx << 8) | (yy << 4) | zz;
            for (uint32_t i = starts[c] + sub, e = starts[c + 1]; i < e; i += 4) {
              float4 p4 = pb[i];
              float d2 = dist2_rn(px, py, pz, p4.x, p4.y, p4.z);
              unsigned long long key =
                  ((unsigned long long)__float_as_uint(d2) << 32) |
                  (unsigned long long)__float_as_uint(p4.w);
              bool i0 = key < bk0, i1 = key < bk1, i2 = key < bk2;
              bk2 = i1 ? bk1 : (i2 ? key : bk2);
              bk1 = i0 ? bk0 : (i1 ? key : bk1);
              bk0 = i0 ? key : bk0;
            }
          }
        }
      }
      merge3(bk0, bk1, bk2, __shfl_xor(bk0, 1), __shfl_xor(bk1, 1), __shfl_xor(bk2, 1));
      merge3(bk0, bk1, bk2, __shfl_xor(bk0, 2), __shfl_xor(bk1, 2), __shfl_xor(bk2, 2));
      t2f = __uint_as_float((uint32_t)(bk2 >> 32));
      float thr = (float)R * H;
      if (t2f < thr * thr * 0.999999f) break;
    }
  }

  if (sub == 0) {
    float d0  = sqrtf(__uint_as_float((uint32_t)(bk0 >> 32)));
    float d1  = sqrtf(__uint_as_float((uint32_t)(bk1 >> 32)));
    float d2s = sqrtf(__uint_as_float((uint32_t)(bk2 >> 32)));
    float r0 = 1.f / (d0 + 1e-8f);
    float r1 = 1.f / (d1 + 1e-8f);
    float r2 = 1.f / (d2s + 1e-8f);
    float inv = 1.f / (r0 + r1 + r2);
    const int jb = b * N_C;
    knn_i[(size_t)dst * 3 + 0] = jb + (int)(bk0 & 0xffffffffull);
    knn_i[(size_t)dst * 3 + 1] = jb + (int)(bk1 & 0xffffffffull);
    knn_i[(size_t)dst * 3 + 2] = jb + (int)(bk2 & 0xffffffffull);
    knn_w[(size_t)dst * 3 + 0] = r0 * inv;
    knn_w[(size_t)dst * 3 + 1] = r1 * inv;
    knn_w[(size_t)dst * 3 + 2] = r2 * inv;
  }
}

// ---------------------------------------------------------------------------
// K3: out = LN(support_feats) @ w1 + b1 + interp(h)   [65536 x 192] x [192 x 192]
// ---------------------------------------------------------------------------
__global__ __launch_bounds__(256) void k3_ln_gemm_interp(
    const float* __restrict__ sfeats, const float* __restrict__ ln_g,
    const float* __restrict__ ln_b, const __bf16* __restrict__ wt1,
    const float* __restrict__ b1, const float* __restrict__ h,
    const int* __restrict__ knn_i, const float* __restrict__ knn_w,
    float* __restrict__ out)
{
  union SMem {
    __bf16 a[64][COUT + 8];    // 25.6 KB — LN'd A-tile (phases 1-2)
    float  c[64][COUT + 4];    // 50.2 KB — staged GEMM result (epilogue)
  };
  __shared__ __align__(16) SMem sm;
  const int tid = threadIdx.x;
  const int blk = blockIdx.x;

  // ---- Phase 1: LN (4 threads/row, 12 float4 each) ----
  {
    const int r = tid >> 2, q = tid & 3;
    const float* frow = sfeats + (size_t)(blk * 64 + r) * COUT;
    float4 v[12];
    float sum = 0.f, sumsq = 0.f;
#pragma unroll
    for (int i = 0; i < 12; ++i) {
      float4 t = *(const float4*)(frow + (q + 4 * i) * 4);
      v[i] = t;
      sum   += (t.x + t.y) + (t.z + t.w);
      sumsq += (t.x * t.x + t.y * t.y) + (t.z * t.z + t.w * t.w);
    }
    sum   += __shfl_xor(sum, 1);  sumsq += __shfl_xor(sumsq, 1);
    sum   += __shfl_xor(sum, 2);  sumsq += __shfl_xor(sumsq, 2);
    float mean = sum * (1.f / COUT);
    float var  = sumsq * (1.f / COUT) - mean * mean;
    if (var < 0.f) var = 0.f;
    float rs = rsqrtf(var + LN_EPS);
#pragma unroll
    for (int i = 0; i < 12; ++i) {
      float4 g4 = *(const float4*)(ln_g + (q + 4 * i) * 4);
      float4 b4 = *(const float4*)(ln_b + (q + 4 * i) * 4);
      bf16x4 o;
      o[0] = (__bf16)((v[i].x - mean) * rs * g4.x + b4.x);
      o[1] = (__bf16)((v[i].y - mean) * rs * g4.y + b4.y);
      o[2] = (__bf16)((v[i].z - mean) * rs * g4.z + b4.z);
      o[3] = (__bf16)((v[i].w - mean) * rs * g4.w + b4.w);
      *(bf16x4*)&sm.a[r][(q + 4 * i) * 4] = o;
    }
  }
  __syncthreads();

  // ---- Phase 2: MFMA ----
  const int w = tid >> 6, lane = tid & 63, m = lane & 15, half = lane >> 4;
  f32x4 acc[12];
#pragma unroll
  for (int t = 0; t < 12; ++t) acc[t] = (f32x4){0.f, 0.f, 0.f, 0.f};

  const __bf16* Arow = &sm.a[16 * w + m][half * 8];
  const __bf16* Bbase = wt1 + (size_t)m * COUT + half * 8;
#pragma unroll
  for (int ch = 0; ch < 6; ++ch) {
    bf16x8 a = *(const bf16x8*)(Arow + ch * 32);
#pragma unroll
    for (int t = 0; t < 12; ++t) {
      bf16x8 b = *(const bf16x8*)(Bbase + (size_t)(16 * t) * COUT + ch * 32);
      acc[t] = __builtin_amdgcn_mfma_f32_16x16x32_bf16(a, b, acc[t], 0, 0, 0);
    }
  }

  // ---- Stage acc+bias into LDS (all waves must be done reading sm.a) ----
  float bv[12];
#pragma unroll
  for (int t = 0; t < 12; ++t) bv[t] = b1[16 * t + m];
  __syncthreads();
  {
    const int rr = 16 * w + half * 4;
#pragma unroll
    for (int t = 0; t < 12; ++t)
#pragma unroll
      for (int reg = 0; reg < 4; ++reg)
        sm.c[rr + reg][16 * t + m] = acc[t][reg] + bv[t];
  }
  __syncthreads();

  // ---- Vectorized interp + store: 4 threads per row, float4 everywhere ----
  {
    const int r = tid >> 2, q = tid & 3;
    const int R = blk * 64 + r;
    int   i0 = knn_i[(size_t)R * 3 + 0];
    int   i1 = knn_i[(size_t)R * 3 + 1];
    int   i2 = knn_i[(size_t)R * 3 + 2];
    float w0 = knn_w[(size_t)R * 3 + 0];
    float w1v = knn_w[(size_t)R * 3 + 1];
    float w2v = knn_w[(size_t)R * 3 + 2];
    const float* h0 = h + (size_t)i0 * COUT;
    const float* h1 = h + (size_t)i1 * COUT;
    const float* h2 = h + (size_t)i2 * COUT;
    float* orow = out + (size_t)R * COUT;
#pragma unroll
    for (int i = 0; i < 12; ++i) {
      const int col = 16 * i + 4 * q;
      f32x4 cv = *(const f32x4*)&sm.c[r][col];
      f32x4 g0 = *(const f32x4*)(h0 + col);
      f32x4 g1 = *(const f32x4*)(h1 + col);
      f32x4 g2 = *(const f32x4*)(h2 + col);
      f32x4 o  = cv + w0 * g0 + w1v * g1 + w2v * g2;
      *(f32x4*)(orow + col) = o;
    }
  }
}

// ---------------------------------------------------------------------------
// K4: passthrough outputs — support_xyz copy + support_offset as float
// ---------------------------------------------------------------------------
__global__ __launch_bounds__(256) void k4_tail(
    const float* __restrict__ sxyz, const int* __restrict__ soff,
    float* __restrict__ out_tail)
{
  const int t = blockIdx.x * 256 + threadIdx.x;
  if (t < MF * 3) out_tail[t] = sxyz[t];
  if (t < B_SEG) out_tail[MF * 3 + t] = (float)soff[t];
}

// ---------------------------------------------------------------------------
extern "C" void kernel_launch(void* const* d_in, const int* in_sizes, int n_in,
                              void* d_out, int out_size, void* d_ws, size_t ws_size,
                              hipStream_t stream)
{
  const float* feats  = (const float*)d_in[0];
  const float* xyz    = (const float*)d_in[1];
  const float* sxyz   = (const float*)d_in[2];
  const float* sfeats = (const float*)d_in[3];
  const int*   soff   = (const int*)d_in[5];
  const float* ln1_g  = (const float*)d_in[6];
  const float* ln1_b  = (const float*)d_in[7];
  const float* w1     = (const float*)d_in[8];
  const float* b1     = (const float*)d_in[9];
  const float* ln2_g  = (const float*)d_in[10];
  const float* ln2_b  = (const float*)d_in[11];
  const float* w2     = (const float*)d_in[12];
  const float* b2     = (const float*)d_in[13];
  float* out = (float*)d_out;

  // workspace layout (float units)
  float*    h       = (float*)d_ws;                        // 16384*192 f32
  int*      knn_i   = (int*)(h + (size_t)MT * COUT);       // 65536*3
  float*    knn_w   = (float*)(knn_i + (size_t)MF * 3);    // 65536*3
  float4*   pts_g   = (float4*)(knn_w + (size_t)MF * 3);   // 4*4096 float4
  uint32_t* starts_g= (uint32_t*)(pts_g + (size_t)B_SEG * N_C);   // 4*4097
  __bf16*   wt2     = (__bf16*)(starts_g + (size_t)B_SEG * (NCELL + 1));
  __bf16*   wt1     = wt2 + (size_t)COUT * CIN;

  k0_prep<<<(CIN * COUT + COUT * COUT) / 256, 256, 0, stream>>>(w2, w1, wt2, wt1);
  kgrid<<<B_SEG, 256, 0, stream>>>(xyz, pts_g, starts_g);
  k1_ln_gemm<<<MT / 64, 256, 0, stream>>>(feats, ln2_g, ln2_b, wt2, b2, h);
  kknn<<<(MF * 4) / 256, 256, 0, stream>>>(sxyz, pts_g, starts_g, knn_i, knn_w);
  k3_ln_gemm_interp<<<MF / 64, 256, 0, stream>>>(sfeats, ln1_g, ln1_b, wt1, b1,
                                                 h, knn_i, knn_w, out);
  k4_tail<<<(MF * 3) / 256, 256, 0, stream>>>(sxyz, soff, out + (size_t)MF * COUT);
}